// Round 9
// baseline (2675.696 us; speedup 1.0000x reference)
//
#include <hip/hip_runtime.h>
#include <hip/hip_fp16.h>

#define NN 50000
#define NE 800000
#define NG 128
#define OUTC 10
#define SCAN_NB ((NN + 255) / 256)  // 196
#define NTILE8 6250                 // 50000 / 8 exactly
#define NODES_PER_PART 6250         // NN / 8
#define FILL_CH 6250                // NE / 128

// ---------------------------------------------------------------- CSR build
__global__ void count_kernel(const int* __restrict__ dst, int* __restrict__ cnt) {
  for (int e = blockIdx.x * blockDim.x + threadIdx.x; e < NE; e += gridDim.x * blockDim.x)
    atomicAdd(&cnt[dst[e]], 1);
}

__global__ __launch_bounds__(256) void partial_kernel(const int* __restrict__ cnt,
                                                      int* __restrict__ part) {
  __shared__ int red[256];
  const int t = threadIdx.x;
  const int idx = blockIdx.x * 256 + t;
  red[t] = (idx < NN) ? cnt[idx] : 0;
  __syncthreads();
#pragma unroll
  for (int off = 128; off > 0; off >>= 1) {
    if (t < off) red[t] += red[t + off];
    __syncthreads();
  }
  if (t == 0) part[blockIdx.x] = red[0];
}

__global__ __launch_bounds__(256) void scanpart_kernel(int* __restrict__ part) {
  __shared__ int s[256];
  const int t = threadIdx.x;
  s[t] = (t < SCAN_NB) ? part[t] : 0;
  __syncthreads();
#pragma unroll
  for (int off = 1; off < 256; off <<= 1) {
    const int v = (t >= off) ? s[t - off] : 0;
    __syncthreads();
    s[t] += v;
    __syncthreads();
  }
  if (t < SCAN_NB) part[t] = (t == 0) ? 0 : s[t - 1];
}

__global__ __launch_bounds__(256) void scatter_scan_kernel(const int* __restrict__ cnt,
                                                           const int* __restrict__ part,
                                                           int* __restrict__ rowptr,
                                                           int* __restrict__ cursor) {
  __shared__ int s[256];
  const int t = threadIdx.x;
  const int idx = blockIdx.x * 256 + t;
  s[t] = (idx < NN) ? cnt[idx] : 0;
  __syncthreads();
#pragma unroll
  for (int off = 1; off < 256; off <<= 1) {
    const int v = (t >= off) ? s[t - off] : 0;
    __syncthreads();
    s[t] += v;
    __syncthreads();
  }
  const int excl = part[blockIdx.x] + ((t == 0) ? 0 : s[t - 1]);
  if (idx < NN) { rowptr[idx] = excl; cursor[idx] = excl; }
  if (idx == 0) rowptr[NN] = NE;
}

// Partitioned fill: block b covers dst-partition (b&7) over edge chunk (b>>3).
__global__ __launch_bounds__(256) void fill_kernel(const int* __restrict__ src,
                                                   const int* __restrict__ dst,
                                                   int* __restrict__ cursor,
                                                   int* __restrict__ esrc) {
  const int p = blockIdx.x & 7;
  const int q = blockIdx.x >> 3;
  const int lo = p * NODES_PER_PART, hi = lo + NODES_PER_PART;
  const int e0 = q * FILL_CH, e1 = e0 + FILL_CH;
  for (int e = e0 + threadIdx.x; e < e1; e += 256) {
    const int d = dst[e];
    if (d >= lo && d < hi) {
      const int pos = atomicAdd(&cursor[d], 1);
      esrc[pos] = src[e];
    }
  }
}

// ------------------------------------- per-graph node counts (batch sorted)
__global__ __launch_bounds__(128) void gbounds_kernel(const int* __restrict__ batch,
                                                      float* __restrict__ gcnt) {
  __shared__ int sb[NG + 1];
  const int g = threadIdx.x;
  int lo = 0, hi = NN;
  while (lo < hi) {
    const int mid = (lo + hi) >> 1;
    if (batch[mid] < g) lo = mid + 1; else hi = mid;
  }
  sb[g] = lo;
  if (g == 0) sb[NG] = NN;
  __syncthreads();
  gcnt[g] = (float)(sb[g + 1] - sb[g]);
}

// ------------------------------------------------- proj: y = x @ W1_0 (fp16)
__global__ __launch_bounds__(256) void proj_kernel(const float* __restrict__ x,
                                                   const float* __restrict__ w1,
                                                   __half* __restrict__ y) {
  __shared__ float sW[128 * 64];
  __shared__ float sX[64 * 128];
  const int t = threadIdx.x, c = t & 63, rg = t >> 6;
  for (int i = t; i < 128 * 64; i += 256) sW[i] = w1[i];
  const int ntiles = (NN + 63) / 64;
  for (int tile = blockIdx.x; tile < ntiles; tile += gridDim.x) {
    const int r0 = tile * 64, nv = min(64, NN - r0);
    __syncthreads();
    for (int i = t; i < nv * 32; i += 256)
      ((float4*)sX)[i] = ((const float4*)(x + (size_t)r0 * 128))[i];
    __syncthreads();
    float acc[16];
#pragma unroll
    for (int i = 0; i < 16; ++i) acc[i] = 0.f;
    for (int k = 0; k < 128; k += 4) {
      const float w0 = sW[(k + 0) * 64 + c], w1v = sW[(k + 1) * 64 + c],
                  w2v = sW[(k + 2) * 64 + c], w3v = sW[(k + 3) * 64 + c];
#pragma unroll
      for (int i = 0; i < 16; ++i) {
        const float4 xv = *(const float4*)&sX[(rg * 16 + i) * 128 + k];
        acc[i] = fmaf(xv.x, w0, acc[i]);
        acc[i] = fmaf(xv.y, w1v, acc[i]);
        acc[i] = fmaf(xv.z, w2v, acc[i]);
        acc[i] = fmaf(xv.w, w3v, acc[i]);
      }
    }
#pragma unroll
    for (int i = 0; i < 16; ++i) {
      const int r = rg * 16 + i;
      if (r < nv) y[(size_t)(r0 + r) * 64 + c] = __float2half(acc[i]);
    }
  }
}

// --------------------------------------- FUSED GIN layer: gather + MLP + pool
// Wave owns 8 rows. Octet o owns row n0+o; its 8 lanes cover all 64 channels
// (16B fp16/lane/edge) -> no cross-lane reduction. Edge loop unrolled x4.
// __launch_bounds__(256, 8): pin VGPR <= 64 (r8 lesson: default min-waves=1
// let the allocator balloon to 256 VGPR -> 9% occupancy -> 90us/layer).
template <bool HASW1, bool WRITEH>
__global__ __launch_bounds__(256, 8) void gin_fused_kernel(
    const __half* __restrict__ hin, const int* __restrict__ rowptr,
    const int* __restrict__ esrc,
    const float* __restrict__ w1, const float* __restrict__ b1,
    const float* __restrict__ w2, const float* __restrict__ b2,
    __half* __restrict__ hout, const int* __restrict__ batch,
    float* __restrict__ gl) {
  __shared__ float sS[4][8 * 64];  // 8KB/block
  const int t = threadIdx.x, c = t & 63, wv = t >> 6;
  const int wg = blockIdx.x * 4 + wv;
  if (wg >= NTILE8) return;  // no barriers anywhere: safe
  float* slice = &sS[wv][0];
  const int n0 = wg * 8;
  const int oct = c >> 3, i = c & 7;  // lane covers channels [i*8, i*8+8)

  // ---- gather phase: row rA = n0 + oct
  const int rA = n0 + oct;
  const int p0 = rowptr[rA], p1 = rowptr[rA + 1];
  union H8 { float4 f; __half2 h2[4]; };
  const __half* hch = hin + i * 8;
  float z[8];
  {
    H8 u; u.f = *(const float4*)(hch + (size_t)rA * 64);  // self term
#pragma unroll
    for (int k = 0; k < 4; ++k) {
      const float2 f = __half22float2(u.h2[k]);
      z[2 * k] = f.x; z[2 * k + 1] = f.y;
    }
  }
  int e = p0;
  for (; e + 3 < p1; e += 4) {
    const int s0 = esrc[e], s1 = esrc[e + 1], s2 = esrc[e + 2], s3 = esrc[e + 3];
    H8 u0, u1, u2, u3;
    u0.f = *(const float4*)(hch + (size_t)s0 * 64);
    u1.f = *(const float4*)(hch + (size_t)s1 * 64);
    u2.f = *(const float4*)(hch + (size_t)s2 * 64);
    u3.f = *(const float4*)(hch + (size_t)s3 * 64);
#pragma unroll
    for (int k = 0; k < 4; ++k) {
      const float2 f0 = __half22float2(u0.h2[k]);
      const float2 f1 = __half22float2(u1.h2[k]);
      const float2 f2 = __half22float2(u2.h2[k]);
      const float2 f3 = __half22float2(u3.h2[k]);
      z[2 * k]     += (f0.x + f1.x) + (f2.x + f3.x);
      z[2 * k + 1] += (f0.y + f1.y) + (f2.y + f3.y);
    }
  }
  for (; e < p1; ++e) {
    H8 u0; u0.f = *(const float4*)(hch + (size_t)esrc[e] * 64);
#pragma unroll
    for (int k = 0; k < 4; ++k) {
      const float2 f0 = __half22float2(u0.h2[k]);
      z[2 * k] += f0.x; z[2 * k + 1] += f0.y;
    }
  }
  if (!HASW1) {  // layer 0 (pre-projected): h1 = relu(z + b1) fused here
    const float4 blo = *(const float4*)(b1 + i * 8);
    const float4 bhi = *(const float4*)(b1 + i * 8 + 4);
    z[0] = fmaxf(z[0] + blo.x, 0.f); z[1] = fmaxf(z[1] + blo.y, 0.f);
    z[2] = fmaxf(z[2] + blo.z, 0.f); z[3] = fmaxf(z[3] + blo.w, 0.f);
    z[4] = fmaxf(z[4] + bhi.x, 0.f); z[5] = fmaxf(z[5] + bhi.y, 0.f);
    z[6] = fmaxf(z[6] + bhi.z, 0.f); z[7] = fmaxf(z[7] + bhi.w, 0.f);
  }
  {
    const float4 a0 = {z[0], z[1], z[2], z[3]};
    const float4 a1 = {z[4], z[5], z[6], z[7]};
    *(float4*)&slice[oct * 64 + i * 8] = a0;
    *(float4*)&slice[oct * 64 + i * 8 + 4] = a1;
  }
  // same-wave LDS: DS pipe is in-order per wave -> no barrier needed

  const float b1c = b1[c], b2c = b2[c];
  // ---- matvec1: h1 = relu(z @ W1 + b1)
  if (HASW1) {
    float acc[8];
#pragma unroll
    for (int r = 0; r < 8; ++r) acc[r] = b1c;
    for (int kc = 0; kc < 4; ++kc) {
      float wr[16];
#pragma unroll
      for (int j = 0; j < 16; ++j) wr[j] = w1[(kc * 16 + j) * 64 + c];
#pragma unroll
      for (int r = 0; r < 8; ++r) {
        const float* zp = &slice[r * 64 + kc * 16];
        const float4 za = *(const float4*)(zp + 0);
        const float4 zb = *(const float4*)(zp + 4);
        const float4 zc = *(const float4*)(zp + 8);
        const float4 zd = *(const float4*)(zp + 12);
        float a = acc[r];
        a = fmaf(za.x, wr[0], a);  a = fmaf(za.y, wr[1], a);
        a = fmaf(za.z, wr[2], a);  a = fmaf(za.w, wr[3], a);
        a = fmaf(zb.x, wr[4], a);  a = fmaf(zb.y, wr[5], a);
        a = fmaf(zb.z, wr[6], a);  a = fmaf(zb.w, wr[7], a);
        a = fmaf(zc.x, wr[8], a);  a = fmaf(zc.y, wr[9], a);
        a = fmaf(zc.z, wr[10], a); a = fmaf(zc.w, wr[11], a);
        a = fmaf(zd.x, wr[12], a); a = fmaf(zd.y, wr[13], a);
        a = fmaf(zd.z, wr[14], a); a = fmaf(zd.w, wr[15], a);
        acc[r] = a;
      }
    }
#pragma unroll
    for (int r = 0; r < 8; ++r) slice[r * 64 + c] = fmaxf(acc[r], 0.f);
  }

  // ---- matvec2: h = relu(h1 @ W2 + b2)
  float acc2[8];
#pragma unroll
  for (int r = 0; r < 8; ++r) acc2[r] = b2c;
  for (int kc = 0; kc < 4; ++kc) {
    float wr[16];
#pragma unroll
    for (int j = 0; j < 16; ++j) wr[j] = w2[(kc * 16 + j) * 64 + c];
#pragma unroll
    for (int r = 0; r < 8; ++r) {
      const float* hp = &slice[r * 64 + kc * 16];
      const float4 za = *(const float4*)(hp + 0);
      const float4 zb = *(const float4*)(hp + 4);
      const float4 zc = *(const float4*)(hp + 8);
      const float4 zd = *(const float4*)(hp + 12);
      float a = acc2[r];
      a = fmaf(za.x, wr[0], a);  a = fmaf(za.y, wr[1], a);
      a = fmaf(za.z, wr[2], a);  a = fmaf(za.w, wr[3], a);
      a = fmaf(zb.x, wr[4], a);  a = fmaf(zb.y, wr[5], a);
      a = fmaf(zb.z, wr[6], a);  a = fmaf(zb.w, wr[7], a);
      a = fmaf(zc.x, wr[8], a);  a = fmaf(zc.y, wr[9], a);
      a = fmaf(zc.z, wr[10], a); a = fmaf(zc.w, wr[11], a);
      a = fmaf(zd.x, wr[12], a); a = fmaf(zd.y, wr[13], a);
      a = fmaf(zd.z, wr[14], a); a = fmaf(zd.w, wr[15], a);
      acc2[r] = a;
    }
  }
  // ---- store (fp16) + fused run-length pooling over sorted batch
  float pacc = 0.f;
  int cur = batch[n0];
#pragma unroll
  for (int r = 0; r < 8; ++r) {
    const float hval = fmaxf(acc2[r], 0.f);
    if (WRITEH) hout[(size_t)(n0 + r) * 64 + c] = __float2half(hval);
    const int b = batch[n0 + r];
    if (b != cur) {
      atomicAdd(&gl[(size_t)cur * 64 + c], pacc);
      pacc = 0.f;
      cur = b;
    }
    pacc += hval;
  }
  atomicAdd(&gl[(size_t)cur * 64 + c], pacc);
}

// ---------------------- JK fold + first classifier matvec (1 graph / block)
__global__ __launch_bounds__(64) void jk_fold_kernel(
    const float* __restrict__ g5, const float* __restrict__ gcnt,
    const float* __restrict__ jkw, const float* __restrict__ jkb,
    const float* __restrict__ w1, const float* __restrict__ b1,
    float* __restrict__ tmat) {
  __shared__ float sg[64];
  const int gi = blockIdx.x, c = threadIdx.x;
  float a = jkb[c] * gcnt[gi];
  for (int l = 0; l < 5; ++l) {
    const float* gv = &g5[(size_t)(l * NG + gi) * 64];
    const float* wv = &jkw[(size_t)l * 64 * 64];
#pragma unroll 8
    for (int k = 0; k < 64; ++k) a = fmaf(gv[k], wv[k * 64 + c], a);
  }
  sg[c] = a;
  __syncthreads();
  float tv = b1[c];
#pragma unroll 8
  for (int k = 0; k < 64; ++k) tv = fmaf(sg[k], w1[k * 64 + c], tv);
  tmat[gi * 64 + c] = tv;
}

// --------------------------------------------- BN (batch stats) + out matvec
__global__ __launch_bounds__(256) void bn_out_kernel(
    const float* __restrict__ tmat, const float* __restrict__ gamma,
    const float* __restrict__ beta, const float* __restrict__ w2,
    const float* __restrict__ b2, float* __restrict__ out) {
  __shared__ float sT[NG * 64];
  __shared__ float sW2[64 * OUTC];
  __shared__ float sMu[64], sRs[64];
  const int t = threadIdx.x;
  for (int i = t; i < NG * 64; i += 256) sT[i] = tmat[i];
  for (int i = t; i < 64 * OUTC; i += 256) sW2[i] = w2[i];
  __syncthreads();
  if (t < 64) {
    float s = 0.f;
    for (int gi = 0; gi < NG; ++gi) s += sT[gi * 64 + t];
    const float mu = s / NG;
    float v = 0.f;
    for (int gi = 0; gi < NG; ++gi) { const float d = sT[gi * 64 + t] - mu; v += d * d; }
    v /= NG;
    sMu[t] = mu;
    sRs[t] = rsqrtf(v + 1e-5f);
  }
  __syncthreads();
  for (int idx = t; idx < NG * 64; idx += 256) {
    const int cc = idx & 63;
    sT[idx] = fmaxf((sT[idx] - sMu[cc]) * sRs[cc] * gamma[cc] + beta[cc], 0.f);
  }
  __syncthreads();
  for (int idx = t; idx < NG * OUTC; idx += 256) {
    const int gi = idx / OUTC, o = idx % OUTC;
    float a = b2[o];
    for (int k = 0; k < 64; ++k) a = fmaf(sT[gi * 64 + k], sW2[k * OUTC + o], a);
    out[idx] = a;
  }
}

// ---------------------------------------------------------------- launch
extern "C" void kernel_launch(void* const* d_in, const int* in_sizes, int n_in,
                              void* d_out, int out_size, void* d_ws, size_t ws_size,
                              hipStream_t stream) {
  const float* x     = (const float*)d_in[0];
  const int*   ei    = (const int*)d_in[1];
  const int*   batch = (const int*)d_in[2];
  const float* w1_0  = (const float*)d_in[3];
  const float* b1_0  = (const float*)d_in[4];
  const float* w2_0  = (const float*)d_in[5];
  const float* b2_0  = (const float*)d_in[6];
  const float* w1_r  = (const float*)d_in[7];
  const float* b1_r  = (const float*)d_in[8];
  const float* w2_r  = (const float*)d_in[9];
  const float* b2_r  = (const float*)d_in[10];
  const float* jk_w  = (const float*)d_in[11];
  const float* jk_b  = (const float*)d_in[12];
  const float* cw1   = (const float*)d_in[13];
  const float* cb1   = (const float*)d_in[14];
  const float* bng   = (const float*)d_in[15];
  const float* bnb   = (const float*)d_in[16];
  const float* cw2   = (const float*)d_in[17];
  const float* cb2   = (const float*)d_in[18];
  float* out = (float*)d_out;

  char* base = (char*)d_ws;
  size_t o = 0;
  auto take = [&](size_t n) { char* p = base + o; o = (o + n + 255) & ~(size_t)255; return p; };
  int*    cnt    = (int*)take((size_t)NN * 4);
  int*    rowptr = (int*)take((size_t)(NN + 1) * 4);
  int*    cursor = (int*)take((size_t)NN * 4);
  int*    part   = (int*)take((size_t)SCAN_NB * 4);
  int*    esrc   = (int*)take((size_t)NE * 4);
  __half* hA     = (__half*)take((size_t)NN * 64 * 2);
  __half* hB     = (__half*)take((size_t)NN * 64 * 2);
  float*  g5     = (float*)take((size_t)5 * NG * 64 * 4);
  float*  gcnt   = (float*)take((size_t)NG * 4);
  float*  tmat   = (float*)take((size_t)NG * 64 * 4);
  (void)ws_size; (void)in_sizes; (void)n_in; (void)out_size;

  hipMemsetAsync(cnt, 0, (size_t)NN * 4, stream);
  hipMemsetAsync(g5, 0, (size_t)5 * NG * 64 * 4, stream);

  const int* src = ei;
  const int* dst = ei + NE;
  count_kernel<<<1024, 256, 0, stream>>>(dst, cnt);
  partial_kernel<<<SCAN_NB, 256, 0, stream>>>(cnt, part);
  scanpart_kernel<<<1, 256, 0, stream>>>(part);
  scatter_scan_kernel<<<SCAN_NB, 256, 0, stream>>>(cnt, part, rowptr, cursor);
  fill_kernel<<<1024, 256, 0, stream>>>(src, dst, cursor, esrc);
  gbounds_kernel<<<1, 128, 0, stream>>>(batch, gcnt);

  const int GRID = (NTILE8 + 3) / 4;  // 1563

  // layer 0 (pre-projected): y = x@W1_0 (into hB fp16), then fused w/o W1
  proj_kernel<<<512, 256, 0, stream>>>(x, w1_0, hB);
  gin_fused_kernel<false, true><<<GRID, 256, 0, stream>>>(
      hB, rowptr, esrc, nullptr, b1_0, w2_0, b2_0, hA, batch, g5);
  const __half* hin = hA;
  __half* hout = hB;
  for (int l = 1; l < 5; ++l) {
    if (l < 4) {
      gin_fused_kernel<true, true><<<GRID, 256, 0, stream>>>(
          hin, rowptr, esrc, w1_r + (size_t)(l - 1) * 64 * 64,
          b1_r + (size_t)(l - 1) * 64, w2_r + (size_t)(l - 1) * 64 * 64,
          b2_r + (size_t)(l - 1) * 64, hout, batch, g5 + (size_t)l * NG * 64);
    } else {
      // last layer: h5 is only pooled -> skip the dead hout store
      gin_fused_kernel<true, false><<<GRID, 256, 0, stream>>>(
          hin, rowptr, esrc, w1_r + (size_t)(l - 1) * 64 * 64,
          b1_r + (size_t)(l - 1) * 64, w2_r + (size_t)(l - 1) * 64 * 64,
          b2_r + (size_t)(l - 1) * 64, hout, batch, g5 + (size_t)l * NG * 64);
    }
    __half* tmp = (__half*)hin;
    hin = hout;
    hout = tmp;
  }

  jk_fold_kernel<<<NG, 64, 0, stream>>>(g5, gcnt, jk_w, jk_b, cw1, cb1, tmat);
  bn_out_kernel<<<1, 256, 0, stream>>>(tmat, bng, bnb, cw2, cb2, out);
}

// Round 10
// 1998.904 us; speedup vs baseline: 1.3386x; 1.3386x over previous
//
#include <hip/hip_runtime.h>
#include <hip/hip_fp16.h>

#define NN 50000
#define NE 800000
#define NG 128
#define OUTC 10
#define SCAN_NB ((NN + 255) / 256)  // 196
#define NTILE8 6250                 // 50000 / 8 exactly
#define NODES_PER_PART 6250         // NN / 8
#define FILL_CH 6250                // NE / 128

// ---------------------------------------------------------------- CSR build
__global__ void count_kernel(const int* __restrict__ dst, int* __restrict__ cnt) {
  for (int e = blockIdx.x * blockDim.x + threadIdx.x; e < NE; e += gridDim.x * blockDim.x)
    atomicAdd(&cnt[dst[e]], 1);
}

__global__ __launch_bounds__(256) void partial_kernel(const int* __restrict__ cnt,
                                                      int* __restrict__ part) {
  __shared__ int red[256];
  const int t = threadIdx.x;
  const int idx = blockIdx.x * 256 + t;
  red[t] = (idx < NN) ? cnt[idx] : 0;
  __syncthreads();
#pragma unroll
  for (int off = 128; off > 0; off >>= 1) {
    if (t < off) red[t] += red[t + off];
    __syncthreads();
  }
  if (t == 0) part[blockIdx.x] = red[0];
}

__global__ __launch_bounds__(256) void scanpart_kernel(int* __restrict__ part) {
  __shared__ int s[256];
  const int t = threadIdx.x;
  s[t] = (t < SCAN_NB) ? part[t] : 0;
  __syncthreads();
#pragma unroll
  for (int off = 1; off < 256; off <<= 1) {
    const int v = (t >= off) ? s[t - off] : 0;
    __syncthreads();
    s[t] += v;
    __syncthreads();
  }
  if (t < SCAN_NB) part[t] = (t == 0) ? 0 : s[t - 1];
}

__global__ __launch_bounds__(256) void scatter_scan_kernel(const int* __restrict__ cnt,
                                                           const int* __restrict__ part,
                                                           int* __restrict__ rowptr,
                                                           int* __restrict__ cursor) {
  __shared__ int s[256];
  const int t = threadIdx.x;
  const int idx = blockIdx.x * 256 + t;
  s[t] = (idx < NN) ? cnt[idx] : 0;
  __syncthreads();
#pragma unroll
  for (int off = 1; off < 256; off <<= 1) {
    const int v = (t >= off) ? s[t - off] : 0;
    __syncthreads();
    s[t] += v;
    __syncthreads();
  }
  const int excl = part[blockIdx.x] + ((t == 0) ? 0 : s[t - 1]);
  if (idx < NN) { rowptr[idx] = excl; cursor[idx] = excl; }
  if (idx == 0) rowptr[NN] = NE;
}

// Partitioned fill: block b covers dst-partition (b&7) over edge chunk (b>>3).
__global__ __launch_bounds__(256) void fill_kernel(const int* __restrict__ src,
                                                   const int* __restrict__ dst,
                                                   int* __restrict__ cursor,
                                                   int* __restrict__ esrc) {
  const int p = blockIdx.x & 7;
  const int q = blockIdx.x >> 3;
  const int lo = p * NODES_PER_PART, hi = lo + NODES_PER_PART;
  const int e0 = q * FILL_CH, e1 = e0 + FILL_CH;
  for (int e = e0 + threadIdx.x; e < e1; e += 256) {
    const int d = dst[e];
    if (d >= lo && d < hi) {
      const int pos = atomicAdd(&cursor[d], 1);
      esrc[pos] = src[e];
    }
  }
}

// ------------------------------------- per-graph node counts (batch sorted)
__global__ __launch_bounds__(128) void gbounds_kernel(const int* __restrict__ batch,
                                                      float* __restrict__ gcnt) {
  __shared__ int sb[NG + 1];
  const int g = threadIdx.x;
  int lo = 0, hi = NN;
  while (lo < hi) {
    const int mid = (lo + hi) >> 1;
    if (batch[mid] < g) lo = mid + 1; else hi = mid;
  }
  sb[g] = lo;
  if (g == 0) sb[NG] = NN;
  __syncthreads();
  gcnt[g] = (float)(sb[g + 1] - sb[g]);
}

// ------------------------------------------------- proj: y = x @ W1_0 (fp16)
__global__ __launch_bounds__(256) void proj_kernel(const float* __restrict__ x,
                                                   const float* __restrict__ w1,
                                                   __half* __restrict__ y) {
  __shared__ float sW[128 * 64];
  __shared__ float sX[64 * 128];
  const int t = threadIdx.x, c = t & 63, rg = t >> 6;
  for (int i = t; i < 128 * 64; i += 256) sW[i] = w1[i];
  const int ntiles = (NN + 63) / 64;
  for (int tile = blockIdx.x; tile < ntiles; tile += gridDim.x) {
    const int r0 = tile * 64, nv = min(64, NN - r0);
    __syncthreads();
    for (int i = t; i < nv * 32; i += 256)
      ((float4*)sX)[i] = ((const float4*)(x + (size_t)r0 * 128))[i];
    __syncthreads();
    float acc[16];
#pragma unroll
    for (int i = 0; i < 16; ++i) acc[i] = 0.f;
    for (int k = 0; k < 128; k += 4) {
      const float w0 = sW[(k + 0) * 64 + c], w1v = sW[(k + 1) * 64 + c],
                  w2v = sW[(k + 2) * 64 + c], w3v = sW[(k + 3) * 64 + c];
#pragma unroll
      for (int i = 0; i < 16; ++i) {
        const float4 xv = *(const float4*)&sX[(rg * 16 + i) * 128 + k];
        acc[i] = fmaf(xv.x, w0, acc[i]);
        acc[i] = fmaf(xv.y, w1v, acc[i]);
        acc[i] = fmaf(xv.z, w2v, acc[i]);
        acc[i] = fmaf(xv.w, w3v, acc[i]);
      }
    }
#pragma unroll
    for (int i = 0; i < 16; ++i) {
      const int r = rg * 16 + i;
      if (r < nv) y[(size_t)(r0 + r) * 64 + c] = __float2half(acc[i]);
    }
  }
}

// --------------------------------------- FUSED GIN layer: gather + MLP + pool
// Wave owns 8 rows. Octet o owns row n0+o; its 8 lanes cover all 64 channels
// (16B fp16/lane/edge) -> no cross-lane reduction. Edge loop unrolled x4.
// __launch_bounds__(256, 4): VGPR cap 128. r8: no bound -> 256 VGPR balloon
// (9% occ). r9: (256,8) -> cap 64, allocator collapsed to 32 + spills
// (805GB scratch traffic!). Natural footprint is 64 VGPR (r7) -> cap 128
// prevents the balloon with headroom, no spill.
template <bool HASW1, bool WRITEH>
__global__ __launch_bounds__(256, 4) void gin_fused_kernel(
    const __half* __restrict__ hin, const int* __restrict__ rowptr,
    const int* __restrict__ esrc,
    const float* __restrict__ w1, const float* __restrict__ b1,
    const float* __restrict__ w2, const float* __restrict__ b2,
    __half* __restrict__ hout, const int* __restrict__ batch,
    float* __restrict__ gl) {
  __shared__ float sS[4][8 * 64];  // 8KB/block
  const int t = threadIdx.x, c = t & 63, wv = t >> 6;
  const int wg = blockIdx.x * 4 + wv;
  if (wg >= NTILE8) return;  // no barriers anywhere: safe
  float* slice = &sS[wv][0];
  const int n0 = wg * 8;
  const int oct = c >> 3, i = c & 7;  // lane covers channels [i*8, i*8+8)

  // ---- gather phase: row rA = n0 + oct
  const int rA = n0 + oct;
  const int p0 = rowptr[rA], p1 = rowptr[rA + 1];
  union H8 { float4 f; __half2 h2[4]; };
  const __half* hch = hin + i * 8;
  float z[8];
  {
    H8 u; u.f = *(const float4*)(hch + (size_t)rA * 64);  // self term
#pragma unroll
    for (int k = 0; k < 4; ++k) {
      const float2 f = __half22float2(u.h2[k]);
      z[2 * k] = f.x; z[2 * k + 1] = f.y;
    }
  }
  int e = p0;
  for (; e + 3 < p1; e += 4) {
    const int s0 = esrc[e], s1 = esrc[e + 1], s2 = esrc[e + 2], s3 = esrc[e + 3];
    H8 u0, u1, u2, u3;
    u0.f = *(const float4*)(hch + (size_t)s0 * 64);
    u1.f = *(const float4*)(hch + (size_t)s1 * 64);
    u2.f = *(const float4*)(hch + (size_t)s2 * 64);
    u3.f = *(const float4*)(hch + (size_t)s3 * 64);
#pragma unroll
    for (int k = 0; k < 4; ++k) {
      const float2 f0 = __half22float2(u0.h2[k]);
      const float2 f1 = __half22float2(u1.h2[k]);
      const float2 f2 = __half22float2(u2.h2[k]);
      const float2 f3 = __half22float2(u3.h2[k]);
      z[2 * k]     += (f0.x + f1.x) + (f2.x + f3.x);
      z[2 * k + 1] += (f0.y + f1.y) + (f2.y + f3.y);
    }
  }
  for (; e < p1; ++e) {
    H8 u0; u0.f = *(const float4*)(hch + (size_t)esrc[e] * 64);
#pragma unroll
    for (int k = 0; k < 4; ++k) {
      const float2 f0 = __half22float2(u0.h2[k]);
      z[2 * k] += f0.x; z[2 * k + 1] += f0.y;
    }
  }
  if (!HASW1) {  // layer 0 (pre-projected): h1 = relu(z + b1) fused here
    const float4 blo = *(const float4*)(b1 + i * 8);
    const float4 bhi = *(const float4*)(b1 + i * 8 + 4);
    z[0] = fmaxf(z[0] + blo.x, 0.f); z[1] = fmaxf(z[1] + blo.y, 0.f);
    z[2] = fmaxf(z[2] + blo.z, 0.f); z[3] = fmaxf(z[3] + blo.w, 0.f);
    z[4] = fmaxf(z[4] + bhi.x, 0.f); z[5] = fmaxf(z[5] + bhi.y, 0.f);
    z[6] = fmaxf(z[6] + bhi.z, 0.f); z[7] = fmaxf(z[7] + bhi.w, 0.f);
  }
  {
    const float4 a0 = {z[0], z[1], z[2], z[3]};
    const float4 a1 = {z[4], z[5], z[6], z[7]};
    *(float4*)&slice[oct * 64 + i * 8] = a0;
    *(float4*)&slice[oct * 64 + i * 8 + 4] = a1;
  }
  // same-wave LDS: DS pipe is in-order per wave -> no barrier needed

  const float b1c = b1[c], b2c = b2[c];
  // ---- matvec1: h1 = relu(z @ W1 + b1)
  if (HASW1) {
    float acc[8];
#pragma unroll
    for (int r = 0; r < 8; ++r) acc[r] = b1c;
    for (int kc = 0; kc < 4; ++kc) {
      float wr[16];
#pragma unroll
      for (int j = 0; j < 16; ++j) wr[j] = w1[(kc * 16 + j) * 64 + c];
#pragma unroll
      for (int r = 0; r < 8; ++r) {
        const float* zp = &slice[r * 64 + kc * 16];
        const float4 za = *(const float4*)(zp + 0);
        const float4 zb = *(const float4*)(zp + 4);
        const float4 zc = *(const float4*)(zp + 8);
        const float4 zd = *(const float4*)(zp + 12);
        float a = acc[r];
        a = fmaf(za.x, wr[0], a);  a = fmaf(za.y, wr[1], a);
        a = fmaf(za.z, wr[2], a);  a = fmaf(za.w, wr[3], a);
        a = fmaf(zb.x, wr[4], a);  a = fmaf(zb.y, wr[5], a);
        a = fmaf(zb.z, wr[6], a);  a = fmaf(zb.w, wr[7], a);
        a = fmaf(zc.x, wr[8], a);  a = fmaf(zc.y, wr[9], a);
        a = fmaf(zc.z, wr[10], a); a = fmaf(zc.w, wr[11], a);
        a = fmaf(zd.x, wr[12], a); a = fmaf(zd.y, wr[13], a);
        a = fmaf(zd.z, wr[14], a); a = fmaf(zd.w, wr[15], a);
        acc[r] = a;
      }
    }
#pragma unroll
    for (int r = 0; r < 8; ++r) slice[r * 64 + c] = fmaxf(acc[r], 0.f);
  }

  // ---- matvec2: h = relu(h1 @ W2 + b2)
  float acc2[8];
#pragma unroll
  for (int r = 0; r < 8; ++r) acc2[r] = b2c;
  for (int kc = 0; kc < 4; ++kc) {
    float wr[16];
#pragma unroll
    for (int j = 0; j < 16; ++j) wr[j] = w2[(kc * 16 + j) * 64 + c];
#pragma unroll
    for (int r = 0; r < 8; ++r) {
      const float* hp = &slice[r * 64 + kc * 16];
      const float4 za = *(const float4*)(hp + 0);
      const float4 zb = *(const float4*)(hp + 4);
      const float4 zc = *(const float4*)(hp + 8);
      const float4 zd = *(const float4*)(hp + 12);
      float a = acc2[r];
      a = fmaf(za.x, wr[0], a);  a = fmaf(za.y, wr[1], a);
      a = fmaf(za.z, wr[2], a);  a = fmaf(za.w, wr[3], a);
      a = fmaf(zb.x, wr[4], a);  a = fmaf(zb.y, wr[5], a);
      a = fmaf(zb.z, wr[6], a);  a = fmaf(zb.w, wr[7], a);
      a = fmaf(zc.x, wr[8], a);  a = fmaf(zc.y, wr[9], a);
      a = fmaf(zc.z, wr[10], a); a = fmaf(zc.w, wr[11], a);
      a = fmaf(zd.x, wr[12], a); a = fmaf(zd.y, wr[13], a);
      a = fmaf(zd.z, wr[14], a); a = fmaf(zd.w, wr[15], a);
      acc2[r] = a;
    }
  }
  // ---- store (fp16) + fused run-length pooling over sorted batch
  float pacc = 0.f;
  int cur = batch[n0];
#pragma unroll
  for (int r = 0; r < 8; ++r) {
    const float hval = fmaxf(acc2[r], 0.f);
    if (WRITEH) hout[(size_t)(n0 + r) * 64 + c] = __float2half(hval);
    const int b = batch[n0 + r];
    if (b != cur) {
      atomicAdd(&gl[(size_t)cur * 64 + c], pacc);
      pacc = 0.f;
      cur = b;
    }
    pacc += hval;
  }
  atomicAdd(&gl[(size_t)cur * 64 + c], pacc);
}

// ---------------------- JK fold + first classifier matvec (1 graph / block)
__global__ __launch_bounds__(64) void jk_fold_kernel(
    const float* __restrict__ g5, const float* __restrict__ gcnt,
    const float* __restrict__ jkw, const float* __restrict__ jkb,
    const float* __restrict__ w1, const float* __restrict__ b1,
    float* __restrict__ tmat) {
  __shared__ float sg[64];
  const int gi = blockIdx.x, c = threadIdx.x;
  float a = jkb[c] * gcnt[gi];
  for (int l = 0; l < 5; ++l) {
    const float* gv = &g5[(size_t)(l * NG + gi) * 64];
    const float* wv = &jkw[(size_t)l * 64 * 64];
#pragma unroll 8
    for (int k = 0; k < 64; ++k) a = fmaf(gv[k], wv[k * 64 + c], a);
  }
  sg[c] = a;
  __syncthreads();
  float tv = b1[c];
#pragma unroll 8
  for (int k = 0; k < 64; ++k) tv = fmaf(sg[k], w1[k * 64 + c], tv);
  tmat[gi * 64 + c] = tv;
}

// --------------------------------------------- BN (batch stats) + out matvec
__global__ __launch_bounds__(256) void bn_out_kernel(
    const float* __restrict__ tmat, const float* __restrict__ gamma,
    const float* __restrict__ beta, const float* __restrict__ w2,
    const float* __restrict__ b2, float* __restrict__ out) {
  __shared__ float sT[NG * 64];
  __shared__ float sW2[64 * OUTC];
  __shared__ float sMu[64], sRs[64];
  const int t = threadIdx.x;
  for (int i = t; i < NG * 64; i += 256) sT[i] = tmat[i];
  for (int i = t; i < 64 * OUTC; i += 256) sW2[i] = w2[i];
  __syncthreads();
  if (t < 64) {
    float s = 0.f;
    for (int gi = 0; gi < NG; ++gi) s += sT[gi * 64 + t];
    const float mu = s / NG;
    float v = 0.f;
    for (int gi = 0; gi < NG; ++gi) { const float d = sT[gi * 64 + t] - mu; v += d * d; }
    v /= NG;
    sMu[t] = mu;
    sRs[t] = rsqrtf(v + 1e-5f);
  }
  __syncthreads();
  for (int idx = t; idx < NG * 64; idx += 256) {
    const int cc = idx & 63;
    sT[idx] = fmaxf((sT[idx] - sMu[cc]) * sRs[cc] * gamma[cc] + beta[cc], 0.f);
  }
  __syncthreads();
  for (int idx = t; idx < NG * OUTC; idx += 256) {
    const int gi = idx / OUTC, o = idx % OUTC;
    float a = b2[o];
    for (int k = 0; k < 64; ++k) a = fmaf(sT[gi * 64 + k], sW2[k * OUTC + o], a);
    out[idx] = a;
  }
}

// ---------------------------------------------------------------- launch
extern "C" void kernel_launch(void* const* d_in, const int* in_sizes, int n_in,
                              void* d_out, int out_size, void* d_ws, size_t ws_size,
                              hipStream_t stream) {
  const float* x     = (const float*)d_in[0];
  const int*   ei    = (const int*)d_in[1];
  const int*   batch = (const int*)d_in[2];
  const float* w1_0  = (const float*)d_in[3];
  const float* b1_0  = (const float*)d_in[4];
  const float* w2_0  = (const float*)d_in[5];
  const float* b2_0  = (const float*)d_in[6];
  const float* w1_r  = (const float*)d_in[7];
  const float* b1_r  = (const float*)d_in[8];
  const float* w2_r  = (const float*)d_in[9];
  const float* b2_r  = (const float*)d_in[10];
  const float* jk_w  = (const float*)d_in[11];
  const float* jk_b  = (const float*)d_in[12];
  const float* cw1   = (const float*)d_in[13];
  const float* cb1   = (const float*)d_in[14];
  const float* bng   = (const float*)d_in[15];
  const float* bnb   = (const float*)d_in[16];
  const float* cw2   = (const float*)d_in[17];
  const float* cb2   = (const float*)d_in[18];
  float* out = (float*)d_out;

  char* base = (char*)d_ws;
  size_t o = 0;
  auto take = [&](size_t n) { char* p = base + o; o = (o + n + 255) & ~(size_t)255; return p; };
  int*    cnt    = (int*)take((size_t)NN * 4);
  int*    rowptr = (int*)take((size_t)(NN + 1) * 4);
  int*    cursor = (int*)take((size_t)NN * 4);
  int*    part   = (int*)take((size_t)SCAN_NB * 4);
  int*    esrc   = (int*)take((size_t)NE * 4);
  __half* hA     = (__half*)take((size_t)NN * 64 * 2);
  __half* hB     = (__half*)take((size_t)NN * 64 * 2);
  float*  g5     = (float*)take((size_t)5 * NG * 64 * 4);
  float*  gcnt   = (float*)take((size_t)NG * 4);
  float*  tmat   = (float*)take((size_t)NG * 64 * 4);
  (void)ws_size; (void)in_sizes; (void)n_in; (void)out_size;

  hipMemsetAsync(cnt, 0, (size_t)NN * 4, stream);
  hipMemsetAsync(g5, 0, (size_t)5 * NG * 64 * 4, stream);

  const int* src = ei;
  const int* dst = ei + NE;
  count_kernel<<<1024, 256, 0, stream>>>(dst, cnt);
  partial_kernel<<<SCAN_NB, 256, 0, stream>>>(cnt, part);
  scanpart_kernel<<<1, 256, 0, stream>>>(part);
  scatter_scan_kernel<<<SCAN_NB, 256, 0, stream>>>(cnt, part, rowptr, cursor);
  fill_kernel<<<1024, 256, 0, stream>>>(src, dst, cursor, esrc);
  gbounds_kernel<<<1, 128, 0, stream>>>(batch, gcnt);

  const int GRID = (NTILE8 + 3) / 4;  // 1563

  // layer 0 (pre-projected): y = x@W1_0 (into hB fp16), then fused w/o W1
  proj_kernel<<<512, 256, 0, stream>>>(x, w1_0, hB);
  gin_fused_kernel<false, true><<<GRID, 256, 0, stream>>>(
      hB, rowptr, esrc, nullptr, b1_0, w2_0, b2_0, hA, batch, g5);
  const __half* hin = hA;
  __half* hout = hB;
  for (int l = 1; l < 5; ++l) {
    if (l < 4) {
      gin_fused_kernel<true, true><<<GRID, 256, 0, stream>>>(
          hin, rowptr, esrc, w1_r + (size_t)(l - 1) * 64 * 64,
          b1_r + (size_t)(l - 1) * 64, w2_r + (size_t)(l - 1) * 64 * 64,
          b2_r + (size_t)(l - 1) * 64, hout, batch, g5 + (size_t)l * NG * 64);
    } else {
      // last layer: h5 is only pooled -> skip the dead hout store
      gin_fused_kernel<true, false><<<GRID, 256, 0, stream>>>(
          hin, rowptr, esrc, w1_r + (size_t)(l - 1) * 64 * 64,
          b1_r + (size_t)(l - 1) * 64, w2_r + (size_t)(l - 1) * 64 * 64,
          b2_r + (size_t)(l - 1) * 64, hout, batch, g5 + (size_t)l * NG * 64);
    }
    __half* tmp = (__half*)hin;
    hin = hout;
    hout = tmp;
  }

  jk_fold_kernel<<<NG, 64, 0, stream>>>(g5, gcnt, jk_w, jk_b, cw1, cb1, tmat);
  bn_out_kernel<<<1, 256, 0, stream>>>(tmat, bng, bnb, cw2, cb2, out);
}

// Round 11
// 399.209 us; speedup vs baseline: 6.7025x; 5.0072x over previous
//
#include <hip/hip_runtime.h>
#include <hip/hip_fp16.h>

#define NN 50000
#define NE 800000
#define NG 128
#define OUTC 10
#define SCAN_NB ((NN + 255) / 256)  // 196
#define NTILE 3125                  // 50000 / 16 exactly
#define NODES_PER_PART 6250         // NN / 8
#define FILL_CH 6250                // NE / 128

// ---------------------------------------------------------------- CSR build
__global__ void count_kernel(const int* __restrict__ dst, int* __restrict__ cnt) {
  for (int e = blockIdx.x * blockDim.x + threadIdx.x; e < NE; e += gridDim.x * blockDim.x)
    atomicAdd(&cnt[dst[e]], 1);
}

__global__ __launch_bounds__(256) void partial_kernel(const int* __restrict__ cnt,
                                                      int* __restrict__ part) {
  __shared__ int red[256];
  const int t = threadIdx.x;
  const int idx = blockIdx.x * 256 + t;
  red[t] = (idx < NN) ? cnt[idx] : 0;
  __syncthreads();
#pragma unroll
  for (int off = 128; off > 0; off >>= 1) {
    if (t < off) red[t] += red[t + off];
    __syncthreads();
  }
  if (t == 0) part[blockIdx.x] = red[0];
}

__global__ __launch_bounds__(256) void scanpart_kernel(int* __restrict__ part) {
  __shared__ int s[256];
  const int t = threadIdx.x;
  s[t] = (t < SCAN_NB) ? part[t] : 0;
  __syncthreads();
#pragma unroll
  for (int off = 1; off < 256; off <<= 1) {
    const int v = (t >= off) ? s[t - off] : 0;
    __syncthreads();
    s[t] += v;
    __syncthreads();
  }
  if (t < SCAN_NB) part[t] = (t == 0) ? 0 : s[t - 1];
}

__global__ __launch_bounds__(256) void scatter_scan_kernel(const int* __restrict__ cnt,
                                                           const int* __restrict__ part,
                                                           int* __restrict__ rowptr,
                                                           int* __restrict__ cursor) {
  __shared__ int s[256];
  const int t = threadIdx.x;
  const int idx = blockIdx.x * 256 + t;
  s[t] = (idx < NN) ? cnt[idx] : 0;
  __syncthreads();
#pragma unroll
  for (int off = 1; off < 256; off <<= 1) {
    const int v = (t >= off) ? s[t - off] : 0;
    __syncthreads();
    s[t] += v;
    __syncthreads();
  }
  const int excl = part[blockIdx.x] + ((t == 0) ? 0 : s[t - 1]);
  if (idx < NN) { rowptr[idx] = excl; cursor[idx] = excl; }
  if (idx == 0) rowptr[NN] = NE;
}

// Partitioned fill: block b covers dst-partition (b&7) over edge chunk (b>>3).
// Writes confined to a 400KB region per partition -> 64B lines fill before
// eviction. dst re-read 8x (sequential, L2/L3-absorbed).
__global__ __launch_bounds__(256) void fill_kernel(const int* __restrict__ src,
                                                   const int* __restrict__ dst,
                                                   int* __restrict__ cursor,
                                                   int* __restrict__ esrc) {
  const int p = blockIdx.x & 7;
  const int q = blockIdx.x >> 3;
  const int lo = p * NODES_PER_PART, hi = lo + NODES_PER_PART;
  const int e0 = q * FILL_CH, e1 = e0 + FILL_CH;
  for (int e = e0 + threadIdx.x; e < e1; e += 256) {
    const int d = dst[e];
    if (d >= lo && d < hi) {
      const int pos = atomicAdd(&cursor[d], 1);
      esrc[pos] = src[e];
    }
  }
}

// ------------------------------------- per-graph node counts (batch sorted)
__global__ __launch_bounds__(128) void gbounds_kernel(const int* __restrict__ batch,
                                                      float* __restrict__ gcnt) {
  __shared__ int sb[NG + 1];
  const int g = threadIdx.x;
  int lo = 0, hi = NN;
  while (lo < hi) {
    const int mid = (lo + hi) >> 1;
    if (batch[mid] < g) lo = mid + 1; else hi = mid;
  }
  sb[g] = lo;
  if (g == 0) sb[NG] = NN;
  __syncthreads();
  gcnt[g] = (float)(sb[g + 1] - sb[g]);
}

// ------------------------------------------------- proj: y = x @ W1_0 (fp16)
__global__ __launch_bounds__(256) void proj_kernel(const float* __restrict__ x,
                                                   const float* __restrict__ w1,
                                                   __half* __restrict__ y) {
  __shared__ float sW[128 * 64];
  __shared__ float sX[64 * 128];
  const int t = threadIdx.x, c = t & 63, rg = t >> 6;
  for (int i = t; i < 128 * 64; i += 256) sW[i] = w1[i];
  const int ntiles = (NN + 63) / 64;
  for (int tile = blockIdx.x; tile < ntiles; tile += gridDim.x) {
    const int r0 = tile * 64, nv = min(64, NN - r0);
    __syncthreads();
    for (int i = t; i < nv * 32; i += 256)
      ((float4*)sX)[i] = ((const float4*)(x + (size_t)r0 * 128))[i];
    __syncthreads();
    float acc[16];
#pragma unroll
    for (int i = 0; i < 16; ++i) acc[i] = 0.f;
    for (int k = 0; k < 128; k += 4) {
      const float w0 = sW[(k + 0) * 64 + c], w1v = sW[(k + 1) * 64 + c],
                  w2v = sW[(k + 2) * 64 + c], w3v = sW[(k + 3) * 64 + c];
#pragma unroll
      for (int i = 0; i < 16; ++i) {
        const float4 xv = *(const float4*)&sX[(rg * 16 + i) * 128 + k];
        acc[i] = fmaf(xv.x, w0, acc[i]);
        acc[i] = fmaf(xv.y, w1v, acc[i]);
        acc[i] = fmaf(xv.z, w2v, acc[i]);
        acc[i] = fmaf(xv.w, w3v, acc[i]);
      }
    }
#pragma unroll
    for (int i = 0; i < 16; ++i) {
      const int r = rg * 16 + i;
      if (r < nv) y[(size_t)(r0 + r) * 64 + c] = __float2half(acc[i]);
    }
  }
}

// --------------------------------------- FUSED GIN layer: gather + MLP + pool
// EXACT round-7 body (proven: 64 VGPR, no spills, ~55us/layer). Wave owns 16
// rows; octet o owns rows {2o, 2o+1}; 8 lanes cover all 64 channels (16B
// fp16/lane/edge) -> no cross-lane reduction. z -> private LDS slice ->
// wave-local matvecs (no barriers). DO NOT restructure to 8-row tiles or add
// launch_bounds min-waves: r8 (no bound) ballooned to 256 VGPR, r9 (256,8)
// spilled at 32 VGPR, r10 (256,4) spilled at 64 VGPR -- all on the 8-row body.
template <bool HASW1, bool WRITEH>
__global__ __launch_bounds__(256) void gin_fused_kernel(
    const __half* __restrict__ hin, const int* __restrict__ rowptr,
    const int* __restrict__ esrc,
    const float* __restrict__ w1, const float* __restrict__ b1,
    const float* __restrict__ w2, const float* __restrict__ b2,
    __half* __restrict__ hout, const int* __restrict__ batch,
    float* __restrict__ gl) {
  __shared__ float sS[4][16 * 64];  // 16KB/block
  const int t = threadIdx.x, c = t & 63, wv = t >> 6;
  const int wg = blockIdx.x * 4 + wv;
  if (wg >= NTILE) return;  // no barriers anywhere: safe
  float* slice = &sS[wv][0];
  const int n0 = wg * 16;
  const int oct = c >> 3, i = c & 7;  // lane covers channels [i*8, i*8+8)

  // ---- gather phase: rows rA = n0+2*oct, rB = rA+1
  const int rA = n0 + 2 * oct;
  const int pA0 = rowptr[rA], pA1 = rowptr[rA + 1], pB1 = rowptr[rA + 2];
  union H8 { float4 f; __half2 h2[4]; };
  const __half* hch = hin + i * 8;
  float zA[8], zB[8];
  {
    H8 u0, u1;
    u0.f = *(const float4*)(hch + (size_t)rA * 64);
    u1.f = *(const float4*)(hch + (size_t)(rA + 1) * 64);
#pragma unroll
    for (int k = 0; k < 4; ++k) {
      const float2 f0 = __half22float2(u0.h2[k]);
      const float2 f1 = __half22float2(u1.h2[k]);
      zA[2 * k] = f0.x; zA[2 * k + 1] = f0.y;
      zB[2 * k] = f1.x; zB[2 * k + 1] = f1.y;
    }
  }
  int e = pA0;
  for (; e + 1 < pA1; e += 2) {
    const int s0 = esrc[e], s1 = esrc[e + 1];
    H8 u0, u1;
    u0.f = *(const float4*)(hch + (size_t)s0 * 64);
    u1.f = *(const float4*)(hch + (size_t)s1 * 64);
#pragma unroll
    for (int k = 0; k < 4; ++k) {
      const float2 f0 = __half22float2(u0.h2[k]);
      const float2 f1 = __half22float2(u1.h2[k]);
      zA[2 * k]     += f0.x + f1.x;
      zA[2 * k + 1] += f0.y + f1.y;
    }
  }
  if (e < pA1) {
    H8 u0; u0.f = *(const float4*)(hch + (size_t)esrc[e] * 64);
#pragma unroll
    for (int k = 0; k < 4; ++k) {
      const float2 f0 = __half22float2(u0.h2[k]);
      zA[2 * k] += f0.x; zA[2 * k + 1] += f0.y;
    }
  }
  e = pA1;
  for (; e + 1 < pB1; e += 2) {
    const int s0 = esrc[e], s1 = esrc[e + 1];
    H8 u0, u1;
    u0.f = *(const float4*)(hch + (size_t)s0 * 64);
    u1.f = *(const float4*)(hch + (size_t)s1 * 64);
#pragma unroll
    for (int k = 0; k < 4; ++k) {
      const float2 f0 = __half22float2(u0.h2[k]);
      const float2 f1 = __half22float2(u1.h2[k]);
      zB[2 * k]     += f0.x + f1.x;
      zB[2 * k + 1] += f0.y + f1.y;
    }
  }
  if (e < pB1) {
    H8 u0; u0.f = *(const float4*)(hch + (size_t)esrc[e] * 64);
#pragma unroll
    for (int k = 0; k < 4; ++k) {
      const float2 f0 = __half22float2(u0.h2[k]);
      zB[2 * k] += f0.x; zB[2 * k + 1] += f0.y;
    }
  }
  if (!HASW1) {  // layer 0 (pre-projected): h1 = relu(z + b1) fused here
    const float4 blo = *(const float4*)(b1 + i * 8);
    const float4 bhi = *(const float4*)(b1 + i * 8 + 4);
    zA[0] = fmaxf(zA[0] + blo.x, 0.f); zA[1] = fmaxf(zA[1] + blo.y, 0.f);
    zA[2] = fmaxf(zA[2] + blo.z, 0.f); zA[3] = fmaxf(zA[3] + blo.w, 0.f);
    zA[4] = fmaxf(zA[4] + bhi.x, 0.f); zA[5] = fmaxf(zA[5] + bhi.y, 0.f);
    zA[6] = fmaxf(zA[6] + bhi.z, 0.f); zA[7] = fmaxf(zA[7] + bhi.w, 0.f);
    zB[0] = fmaxf(zB[0] + blo.x, 0.f); zB[1] = fmaxf(zB[1] + blo.y, 0.f);
    zB[2] = fmaxf(zB[2] + blo.z, 0.f); zB[3] = fmaxf(zB[3] + blo.w, 0.f);
    zB[4] = fmaxf(zB[4] + bhi.x, 0.f); zB[5] = fmaxf(zB[5] + bhi.y, 0.f);
    zB[6] = fmaxf(zB[6] + bhi.z, 0.f); zB[7] = fmaxf(zB[7] + bhi.w, 0.f);
  }
  {
    const float4 a0 = {zA[0], zA[1], zA[2], zA[3]};
    const float4 a1 = {zA[4], zA[5], zA[6], zA[7]};
    const float4 b0v = {zB[0], zB[1], zB[2], zB[3]};
    const float4 b1v_ = {zB[4], zB[5], zB[6], zB[7]};
    *(float4*)&slice[(2 * oct) * 64 + i * 8] = a0;
    *(float4*)&slice[(2 * oct) * 64 + i * 8 + 4] = a1;
    *(float4*)&slice[(2 * oct + 1) * 64 + i * 8] = b0v;
    *(float4*)&slice[(2 * oct + 1) * 64 + i * 8 + 4] = b1v_;
  }
  // same-wave LDS: DS pipe is in-order per wave -> no barrier needed

  const float b1c = b1[c], b2c = b2[c];
  // ---- matvec1: h1 = relu(z @ W1 + b1)
  if (HASW1) {
    float acc[16];
#pragma unroll
    for (int r = 0; r < 16; ++r) acc[r] = b1c;
    for (int kc = 0; kc < 4; ++kc) {
      float wr[16];
#pragma unroll
      for (int j = 0; j < 16; ++j) wr[j] = w1[(kc * 16 + j) * 64 + c];
#pragma unroll
      for (int r = 0; r < 16; ++r) {
        const float* zp = &slice[r * 64 + kc * 16];
        const float4 za = *(const float4*)(zp + 0);
        const float4 zb = *(const float4*)(zp + 4);
        const float4 zc = *(const float4*)(zp + 8);
        const float4 zd = *(const float4*)(zp + 12);
        float a = acc[r];
        a = fmaf(za.x, wr[0], a);  a = fmaf(za.y, wr[1], a);
        a = fmaf(za.z, wr[2], a);  a = fmaf(za.w, wr[3], a);
        a = fmaf(zb.x, wr[4], a);  a = fmaf(zb.y, wr[5], a);
        a = fmaf(zb.z, wr[6], a);  a = fmaf(zb.w, wr[7], a);
        a = fmaf(zc.x, wr[8], a);  a = fmaf(zc.y, wr[9], a);
        a = fmaf(zc.z, wr[10], a); a = fmaf(zc.w, wr[11], a);
        a = fmaf(zd.x, wr[12], a); a = fmaf(zd.y, wr[13], a);
        a = fmaf(zd.z, wr[14], a); a = fmaf(zd.w, wr[15], a);
        acc[r] = a;
      }
    }
#pragma unroll
    for (int r = 0; r < 16; ++r) slice[r * 64 + c] = fmaxf(acc[r], 0.f);
  }

  // ---- matvec2: h = relu(h1 @ W2 + b2)
  float acc2[16];
#pragma unroll
  for (int r = 0; r < 16; ++r) acc2[r] = b2c;
  for (int kc = 0; kc < 4; ++kc) {
    float wr[16];
#pragma unroll
    for (int j = 0; j < 16; ++j) wr[j] = w2[(kc * 16 + j) * 64 + c];
#pragma unroll
    for (int r = 0; r < 16; ++r) {
      const float* hp = &slice[r * 64 + kc * 16];
      const float4 za = *(const float4*)(hp + 0);
      const float4 zb = *(const float4*)(hp + 4);
      const float4 zc = *(const float4*)(hp + 8);
      const float4 zd = *(const float4*)(hp + 12);
      float a = acc2[r];
      a = fmaf(za.x, wr[0], a);  a = fmaf(za.y, wr[1], a);
      a = fmaf(za.z, wr[2], a);  a = fmaf(za.w, wr[3], a);
      a = fmaf(zb.x, wr[4], a);  a = fmaf(zb.y, wr[5], a);
      a = fmaf(zb.z, wr[6], a);  a = fmaf(zb.w, wr[7], a);
      a = fmaf(zc.x, wr[8], a);  a = fmaf(zc.y, wr[9], a);
      a = fmaf(zc.z, wr[10], a); a = fmaf(zc.w, wr[11], a);
      a = fmaf(zd.x, wr[12], a); a = fmaf(zd.y, wr[13], a);
      a = fmaf(zd.z, wr[14], a); a = fmaf(zd.w, wr[15], a);
      acc2[r] = a;
    }
  }
  // ---- store (fp16) + fused run-length pooling over sorted batch
  float pacc = 0.f;
  int cur = batch[n0];
#pragma unroll
  for (int r = 0; r < 16; ++r) {
    const float hval = fmaxf(acc2[r], 0.f);
    if (WRITEH) hout[(size_t)(n0 + r) * 64 + c] = __float2half(hval);
    const int b = batch[n0 + r];
    if (b != cur) {
      atomicAdd(&gl[(size_t)cur * 64 + c], pacc);
      pacc = 0.f;
      cur = b;
    }
    pacc += hval;
  }
  atomicAdd(&gl[(size_t)cur * 64 + c], pacc);
}

// ---------------------- JK fold + first classifier matvec (1 graph / block)
__global__ __launch_bounds__(64) void jk_fold_kernel(
    const float* __restrict__ g5, const float* __restrict__ gcnt,
    const float* __restrict__ jkw, const float* __restrict__ jkb,
    const float* __restrict__ w1, const float* __restrict__ b1,
    float* __restrict__ tmat) {
  __shared__ float sg[64];
  const int gi = blockIdx.x, c = threadIdx.x;
  float a = jkb[c] * gcnt[gi];
  for (int l = 0; l < 5; ++l) {
    const float* gv = &g5[(size_t)(l * NG + gi) * 64];
    const float* wv = &jkw[(size_t)l * 64 * 64];
#pragma unroll 8
    for (int k = 0; k < 64; ++k) a = fmaf(gv[k], wv[k * 64 + c], a);
  }
  sg[c] = a;
  __syncthreads();
  float tv = b1[c];
#pragma unroll 8
  for (int k = 0; k < 64; ++k) tv = fmaf(sg[k], w1[k * 64 + c], tv);
  tmat[gi * 64 + c] = tv;
}

// --------------------------------------------- BN (batch stats) + out matvec
__global__ __launch_bounds__(256) void bn_out_kernel(
    const float* __restrict__ tmat, const float* __restrict__ gamma,
    const float* __restrict__ beta, const float* __restrict__ w2,
    const float* __restrict__ b2, float* __restrict__ out) {
  __shared__ float sT[NG * 64];
  __shared__ float sW2[64 * OUTC];
  __shared__ float sMu[64], sRs[64];
  const int t = threadIdx.x;
  for (int i = t; i < NG * 64; i += 256) sT[i] = tmat[i];
  for (int i = t; i < 64 * OUTC; i += 256) sW2[i] = w2[i];
  __syncthreads();
  if (t < 64) {
    float s = 0.f;
    for (int gi = 0; gi < NG; ++gi) s += sT[gi * 64 + t];
    const float mu = s / NG;
    float v = 0.f;
    for (int gi = 0; gi < NG; ++gi) { const float d = sT[gi * 64 + t] - mu; v += d * d; }
    v /= NG;
    sMu[t] = mu;
    sRs[t] = rsqrtf(v + 1e-5f);
  }
  __syncthreads();
  for (int idx = t; idx < NG * 64; idx += 256) {
    const int cc = idx & 63;
    sT[idx] = fmaxf((sT[idx] - sMu[cc]) * sRs[cc] * gamma[cc] + beta[cc], 0.f);
  }
  __syncthreads();
  for (int idx = t; idx < NG * OUTC; idx += 256) {
    const int gi = idx / OUTC, o = idx % OUTC;
    float a = b2[o];
    for (int k = 0; k < 64; ++k) a = fmaf(sT[gi * 64 + k], sW2[k * OUTC + o], a);
    out[idx] = a;
  }
}

// ---------------------------------------------------------------- launch
extern "C" void kernel_launch(void* const* d_in, const int* in_sizes, int n_in,
                              void* d_out, int out_size, void* d_ws, size_t ws_size,
                              hipStream_t stream) {
  const float* x     = (const float*)d_in[0];
  const int*   ei    = (const int*)d_in[1];
  const int*   batch = (const int*)d_in[2];
  const float* w1_0  = (const float*)d_in[3];
  const float* b1_0  = (const float*)d_in[4];
  const float* w2_0  = (const float*)d_in[5];
  const float* b2_0  = (const float*)d_in[6];
  const float* w1_r  = (const float*)d_in[7];
  const float* b1_r  = (const float*)d_in[8];
  const float* w2_r  = (const float*)d_in[9];
  const float* b2_r  = (const float*)d_in[10];
  const float* jk_w  = (const float*)d_in[11];
  const float* jk_b  = (const float*)d_in[12];
  const float* cw1   = (const float*)d_in[13];
  const float* cb1   = (const float*)d_in[14];
  const float* bng   = (const float*)d_in[15];
  const float* bnb   = (const float*)d_in[16];
  const float* cw2   = (const float*)d_in[17];
  const float* cb2   = (const float*)d_in[18];
  float* out = (float*)d_out;

  char* base = (char*)d_ws;
  size_t o = 0;
  auto take = [&](size_t n) { char* p = base + o; o = (o + n + 255) & ~(size_t)255; return p; };
  int*    cnt    = (int*)take((size_t)NN * 4);
  int*    rowptr = (int*)take((size_t)(NN + 1) * 4);
  int*    cursor = (int*)take((size_t)NN * 4);
  int*    part   = (int*)take((size_t)SCAN_NB * 4);
  int*    esrc   = (int*)take((size_t)NE * 4);
  __half* hA     = (__half*)take((size_t)NN * 64 * 2);
  __half* hB     = (__half*)take((size_t)NN * 64 * 2);
  float*  g5     = (float*)take((size_t)5 * NG * 64 * 4);
  float*  gcnt   = (float*)take((size_t)NG * 4);
  float*  tmat   = (float*)take((size_t)NG * 64 * 4);
  (void)ws_size; (void)in_sizes; (void)n_in; (void)out_size;

  hipMemsetAsync(cnt, 0, (size_t)NN * 4, stream);
  hipMemsetAsync(g5, 0, (size_t)5 * NG * 64 * 4, stream);

  const int* src = ei;
  const int* dst = ei + NE;
  count_kernel<<<1024, 256, 0, stream>>>(dst, cnt);
  partial_kernel<<<SCAN_NB, 256, 0, stream>>>(cnt, part);
  scanpart_kernel<<<1, 256, 0, stream>>>(part);
  scatter_scan_kernel<<<SCAN_NB, 256, 0, stream>>>(cnt, part, rowptr, cursor);
  fill_kernel<<<1024, 256, 0, stream>>>(src, dst, cursor, esrc);
  gbounds_kernel<<<1, 128, 0, stream>>>(batch, gcnt);

  const int GRID = (NTILE + 3) / 4;  // 782

  // layer 0 (pre-projected): y = x@W1_0 (into hB fp16), then fused w/o W1
  proj_kernel<<<512, 256, 0, stream>>>(x, w1_0, hB);
  gin_fused_kernel<false, true><<<GRID, 256, 0, stream>>>(
      hB, rowptr, esrc, nullptr, b1_0, w2_0, b2_0, hA, batch, g5);
  const __half* hin = hA;
  __half* hout = hB;
  for (int l = 1; l < 5; ++l) {
    if (l < 4) {
      gin_fused_kernel<true, true><<<GRID, 256, 0, stream>>>(
          hin, rowptr, esrc, w1_r + (size_t)(l - 1) * 64 * 64,
          b1_r + (size_t)(l - 1) * 64, w2_r + (size_t)(l - 1) * 64 * 64,
          b2_r + (size_t)(l - 1) * 64, hout, batch, g5 + (size_t)l * NG * 64);
    } else {
      // last layer: h5 is only pooled -> skip the dead hout store
      gin_fused_kernel<true, false><<<GRID, 256, 0, stream>>>(
          hin, rowptr, esrc, w1_r + (size_t)(l - 1) * 64 * 64,
          b1_r + (size_t)(l - 1) * 64, w2_r + (size_t)(l - 1) * 64 * 64,
          b2_r + (size_t)(l - 1) * 64, hout, batch, g5 + (size_t)l * NG * 64);
    }
    __half* tmp = (__half*)hin;
    hin = hout;
    hout = tmp;
  }

  jk_fold_kernel<<<NG, 64, 0, stream>>>(g5, gcnt, jk_w, jk_b, cw1, cb1, tmat);
  bn_out_kernel<<<1, 256, 0, stream>>>(tmat, bng, bnb, cw2, cb2, out);
}

// Round 12
// 395.267 us; speedup vs baseline: 6.7693x; 1.0100x over previous
//
#include <hip/hip_runtime.h>
#include <hip/hip_fp16.h>

#define NN 50000
#define NE 800000
#define NG 128
#define OUTC 10
#define SCAN_NB ((NN + 255) / 256)  // 196
#define NTILE 3125                  // 50000 / 16 exactly
#define NODES_PER_PART 6250         // NN / 8
#define FILL_CH 6250                // NE / 128

// ---------------------------------------------------------------- CSR build
__global__ void count_kernel(const int* __restrict__ dst, int* __restrict__ cnt) {
  for (int e = blockIdx.x * blockDim.x + threadIdx.x; e < NE; e += gridDim.x * blockDim.x)
    atomicAdd(&cnt[dst[e]], 1);
}

__global__ __launch_bounds__(256) void partial_kernel(const int* __restrict__ cnt,
                                                      int* __restrict__ part) {
  __shared__ int red[256];
  const int t = threadIdx.x;
  const int idx = blockIdx.x * 256 + t;
  red[t] = (idx < NN) ? cnt[idx] : 0;
  __syncthreads();
#pragma unroll
  for (int off = 128; off > 0; off >>= 1) {
    if (t < off) red[t] += red[t + off];
    __syncthreads();
  }
  if (t == 0) part[blockIdx.x] = red[0];
}

__global__ __launch_bounds__(256) void scanpart_kernel(int* __restrict__ part) {
  __shared__ int s[256];
  const int t = threadIdx.x;
  s[t] = (t < SCAN_NB) ? part[t] : 0;
  __syncthreads();
#pragma unroll
  for (int off = 1; off < 256; off <<= 1) {
    const int v = (t >= off) ? s[t - off] : 0;
    __syncthreads();
    s[t] += v;
    __syncthreads();
  }
  if (t < SCAN_NB) part[t] = (t == 0) ? 0 : s[t - 1];
}

__global__ __launch_bounds__(256) void scatter_scan_kernel(const int* __restrict__ cnt,
                                                           const int* __restrict__ part,
                                                           int* __restrict__ rowptr,
                                                           int* __restrict__ cursor) {
  __shared__ int s[256];
  const int t = threadIdx.x;
  const int idx = blockIdx.x * 256 + t;
  s[t] = (idx < NN) ? cnt[idx] : 0;
  __syncthreads();
#pragma unroll
  for (int off = 1; off < 256; off <<= 1) {
    const int v = (t >= off) ? s[t - off] : 0;
    __syncthreads();
    s[t] += v;
    __syncthreads();
  }
  const int excl = part[blockIdx.x] + ((t == 0) ? 0 : s[t - 1]);
  if (idx < NN) { rowptr[idx] = excl; cursor[idx] = excl; }
  if (idx == 0) rowptr[NN] = NE;
}

// Partitioned fill: block b covers dst-partition (b&7) over edge chunk (b>>3).
__global__ __launch_bounds__(256) void fill_kernel(const int* __restrict__ src,
                                                   const int* __restrict__ dst,
                                                   int* __restrict__ cursor,
                                                   int* __restrict__ esrc) {
  const int p = blockIdx.x & 7;
  const int q = blockIdx.x >> 3;
  const int lo = p * NODES_PER_PART, hi = lo + NODES_PER_PART;
  const int e0 = q * FILL_CH, e1 = e0 + FILL_CH;
  for (int e = e0 + threadIdx.x; e < e1; e += 256) {
    const int d = dst[e];
    if (d >= lo && d < hi) {
      const int pos = atomicAdd(&cursor[d], 1);
      esrc[pos] = src[e];
    }
  }
}

// ------------------------------------- per-graph node counts (batch sorted)
__global__ __launch_bounds__(128) void gbounds_kernel(const int* __restrict__ batch,
                                                      float* __restrict__ gcnt) {
  __shared__ int sb[NG + 1];
  const int g = threadIdx.x;
  int lo = 0, hi = NN;
  while (lo < hi) {
    const int mid = (lo + hi) >> 1;
    if (batch[mid] < g) lo = mid + 1; else hi = mid;
  }
  sb[g] = lo;
  if (g == 0) sb[NG] = NN;
  __syncthreads();
  gcnt[g] = (float)(sb[g + 1] - sb[g]);
}

// ------------------------------------------------- proj: y = x @ W1_0 (fp16)
__global__ __launch_bounds__(256) void proj_kernel(const float* __restrict__ x,
                                                   const float* __restrict__ w1,
                                                   __half* __restrict__ y) {
  __shared__ float sW[128 * 64];
  __shared__ float sX[64 * 128];
  const int t = threadIdx.x, c = t & 63, rg = t >> 6;
  for (int i = t; i < 128 * 64; i += 256) sW[i] = w1[i];
  const int ntiles = (NN + 63) / 64;
  for (int tile = blockIdx.x; tile < ntiles; tile += gridDim.x) {
    const int r0 = tile * 64, nv = min(64, NN - r0);
    __syncthreads();
    for (int i = t; i < nv * 32; i += 256)
      ((float4*)sX)[i] = ((const float4*)(x + (size_t)r0 * 128))[i];
    __syncthreads();
    float acc[16];
#pragma unroll
    for (int i = 0; i < 16; ++i) acc[i] = 0.f;
    for (int k = 0; k < 128; k += 4) {
      const float w0 = sW[(k + 0) * 64 + c], w1v = sW[(k + 1) * 64 + c],
                  w2v = sW[(k + 2) * 64 + c], w3v = sW[(k + 3) * 64 + c];
#pragma unroll
      for (int i = 0; i < 16; ++i) {
        const float4 xv = *(const float4*)&sX[(rg * 16 + i) * 128 + k];
        acc[i] = fmaf(xv.x, w0, acc[i]);
        acc[i] = fmaf(xv.y, w1v, acc[i]);
        acc[i] = fmaf(xv.z, w2v, acc[i]);
        acc[i] = fmaf(xv.w, w3v, acc[i]);
      }
    }
#pragma unroll
    for (int i = 0; i < 16; ++i) {
      const int r = rg * 16 + i;
      if (r < nv) y[(size_t)(r0 + r) * 64 + c] = __float2half(acc[i]);
    }
  }
}

// --------------------------------------- FUSED GIN layer: gather + MLP + pool
// r7/r11 body with ONE change: the two per-octet row streams (zA, zB) are
// interleaved in a main loop -> 4 row-loads in flight per lane (was 2).
// Tile geometry, lane mapping, accumulators, matvecs: byte-identical to r11.
// DO NOT restructure tiles or add launch_bounds min-waves (r8/r9/r10 lessons).
template <bool HASW1, bool WRITEH>
__global__ __launch_bounds__(256) void gin_fused_kernel(
    const __half* __restrict__ hin, const int* __restrict__ rowptr,
    const int* __restrict__ esrc,
    const float* __restrict__ w1, const float* __restrict__ b1,
    const float* __restrict__ w2, const float* __restrict__ b2,
    __half* __restrict__ hout, const int* __restrict__ batch,
    float* __restrict__ gl) {
  __shared__ float sS[4][16 * 64];  // 16KB/block
  const int t = threadIdx.x, c = t & 63, wv = t >> 6;
  const int wg = blockIdx.x * 4 + wv;
  if (wg >= NTILE) return;  // no barriers anywhere: safe
  float* slice = &sS[wv][0];
  const int n0 = wg * 16;
  const int oct = c >> 3, i = c & 7;  // lane covers channels [i*8, i*8+8)

  // ---- gather phase: rows rA = n0+2*oct, rB = rA+1
  const int rA = n0 + 2 * oct;
  const int pA0 = rowptr[rA], pA1 = rowptr[rA + 1], pB1 = rowptr[rA + 2];
  union H8 { float4 f; __half2 h2[4]; };
  const __half* hch = hin + i * 8;
  float zA[8], zB[8];
  {
    H8 u0, u1;
    u0.f = *(const float4*)(hch + (size_t)rA * 64);
    u1.f = *(const float4*)(hch + (size_t)(rA + 1) * 64);
#pragma unroll
    for (int k = 0; k < 4; ++k) {
      const float2 f0 = __half22float2(u0.h2[k]);
      const float2 f1 = __half22float2(u1.h2[k]);
      zA[2 * k] = f0.x; zA[2 * k + 1] = f0.y;
      zB[2 * k] = f1.x; zB[2 * k + 1] = f1.y;
    }
  }
  int eA = pA0, eB = pA1;
  // main loop: interleave streams A and B -> 4 independent row loads in flight
  while (eA + 1 < pA1 && eB + 1 < pB1) {
    const int sA0 = esrc[eA], sA1 = esrc[eA + 1];
    const int sB0 = esrc[eB], sB1 = esrc[eB + 1];
    H8 a0, a1, b0, b1v;
    a0.f = *(const float4*)(hch + (size_t)sA0 * 64);
    a1.f = *(const float4*)(hch + (size_t)sA1 * 64);
    b0.f = *(const float4*)(hch + (size_t)sB0 * 64);
    b1v.f = *(const float4*)(hch + (size_t)sB1 * 64);
#pragma unroll
    for (int k = 0; k < 4; ++k) {
      const float2 fa0 = __half22float2(a0.h2[k]);
      const float2 fa1 = __half22float2(a1.h2[k]);
      const float2 fb0 = __half22float2(b0.h2[k]);
      const float2 fb1 = __half22float2(b1v.h2[k]);
      zA[2 * k]     += fa0.x + fa1.x;
      zA[2 * k + 1] += fa0.y + fa1.y;
      zB[2 * k]     += fb0.x + fb1.x;
      zB[2 * k + 1] += fb0.y + fb1.y;
    }
    eA += 2; eB += 2;
  }
  // tails: exact r7 loops from current cursors
  for (; eA + 1 < pA1; eA += 2) {
    const int s0 = esrc[eA], s1 = esrc[eA + 1];
    H8 u0, u1;
    u0.f = *(const float4*)(hch + (size_t)s0 * 64);
    u1.f = *(const float4*)(hch + (size_t)s1 * 64);
#pragma unroll
    for (int k = 0; k < 4; ++k) {
      const float2 f0 = __half22float2(u0.h2[k]);
      const float2 f1 = __half22float2(u1.h2[k]);
      zA[2 * k]     += f0.x + f1.x;
      zA[2 * k + 1] += f0.y + f1.y;
    }
  }
  if (eA < pA1) {
    H8 u0; u0.f = *(const float4*)(hch + (size_t)esrc[eA] * 64);
#pragma unroll
    for (int k = 0; k < 4; ++k) {
      const float2 f0 = __half22float2(u0.h2[k]);
      zA[2 * k] += f0.x; zA[2 * k + 1] += f0.y;
    }
  }
  for (; eB + 1 < pB1; eB += 2) {
    const int s0 = esrc[eB], s1 = esrc[eB + 1];
    H8 u0, u1;
    u0.f = *(const float4*)(hch + (size_t)s0 * 64);
    u1.f = *(const float4*)(hch + (size_t)s1 * 64);
#pragma unroll
    for (int k = 0; k < 4; ++k) {
      const float2 f0 = __half22float2(u0.h2[k]);
      const float2 f1 = __half22float2(u1.h2[k]);
      zB[2 * k]     += f0.x + f1.x;
      zB[2 * k + 1] += f0.y + f1.y;
    }
  }
  if (eB < pB1) {
    H8 u0; u0.f = *(const float4*)(hch + (size_t)esrc[eB] * 64);
#pragma unroll
    for (int k = 0; k < 4; ++k) {
      const float2 f0 = __half22float2(u0.h2[k]);
      zB[2 * k] += f0.x; zB[2 * k + 1] += f0.y;
    }
  }
  if (!HASW1) {  // layer 0 (pre-projected): h1 = relu(z + b1) fused here
    const float4 blo = *(const float4*)(b1 + i * 8);
    const float4 bhi = *(const float4*)(b1 + i * 8 + 4);
    zA[0] = fmaxf(zA[0] + blo.x, 0.f); zA[1] = fmaxf(zA[1] + blo.y, 0.f);
    zA[2] = fmaxf(zA[2] + blo.z, 0.f); zA[3] = fmaxf(zA[3] + blo.w, 0.f);
    zA[4] = fmaxf(zA[4] + bhi.x, 0.f); zA[5] = fmaxf(zA[5] + bhi.y, 0.f);
    zA[6] = fmaxf(zA[6] + bhi.z, 0.f); zA[7] = fmaxf(zA[7] + bhi.w, 0.f);
    zB[0] = fmaxf(zB[0] + blo.x, 0.f); zB[1] = fmaxf(zB[1] + blo.y, 0.f);
    zB[2] = fmaxf(zB[2] + blo.z, 0.f); zB[3] = fmaxf(zB[3] + blo.w, 0.f);
    zB[4] = fmaxf(zB[4] + bhi.x, 0.f); zB[5] = fmaxf(zB[5] + bhi.y, 0.f);
    zB[6] = fmaxf(zB[6] + bhi.z, 0.f); zB[7] = fmaxf(zB[7] + bhi.w, 0.f);
  }
  {
    const float4 a0 = {zA[0], zA[1], zA[2], zA[3]};
    const float4 a1 = {zA[4], zA[5], zA[6], zA[7]};
    const float4 b0v = {zB[0], zB[1], zB[2], zB[3]};
    const float4 b1v_ = {zB[4], zB[5], zB[6], zB[7]};
    *(float4*)&slice[(2 * oct) * 64 + i * 8] = a0;
    *(float4*)&slice[(2 * oct) * 64 + i * 8 + 4] = a1;
    *(float4*)&slice[(2 * oct + 1) * 64 + i * 8] = b0v;
    *(float4*)&slice[(2 * oct + 1) * 64 + i * 8 + 4] = b1v_;
  }
  // same-wave LDS: DS pipe is in-order per wave -> no barrier needed

  const float b1c = b1[c], b2c = b2[c];
  // ---- matvec1: h1 = relu(z @ W1 + b1)
  if (HASW1) {
    float acc[16];
#pragma unroll
    for (int r = 0; r < 16; ++r) acc[r] = b1c;
    for (int kc = 0; kc < 4; ++kc) {
      float wr[16];
#pragma unroll
      for (int j = 0; j < 16; ++j) wr[j] = w1[(kc * 16 + j) * 64 + c];
#pragma unroll
      for (int r = 0; r < 16; ++r) {
        const float* zp = &slice[r * 64 + kc * 16];
        const float4 za = *(const float4*)(zp + 0);
        const float4 zb = *(const float4*)(zp + 4);
        const float4 zc = *(const float4*)(zp + 8);
        const float4 zd = *(const float4*)(zp + 12);
        float a = acc[r];
        a = fmaf(za.x, wr[0], a);  a = fmaf(za.y, wr[1], a);
        a = fmaf(za.z, wr[2], a);  a = fmaf(za.w, wr[3], a);
        a = fmaf(zb.x, wr[4], a);  a = fmaf(zb.y, wr[5], a);
        a = fmaf(zb.z, wr[6], a);  a = fmaf(zb.w, wr[7], a);
        a = fmaf(zc.x, wr[8], a);  a = fmaf(zc.y, wr[9], a);
        a = fmaf(zc.z, wr[10], a); a = fmaf(zc.w, wr[11], a);
        a = fmaf(zd.x, wr[12], a); a = fmaf(zd.y, wr[13], a);
        a = fmaf(zd.z, wr[14], a); a = fmaf(zd.w, wr[15], a);
        acc[r] = a;
      }
    }
#pragma unroll
    for (int r = 0; r < 16; ++r) slice[r * 64 + c] = fmaxf(acc[r], 0.f);
  }

  // ---- matvec2: h = relu(h1 @ W2 + b2)
  float acc2[16];
#pragma unroll
  for (int r = 0; r < 16; ++r) acc2[r] = b2c;
  for (int kc = 0; kc < 4; ++kc) {
    float wr[16];
#pragma unroll
    for (int j = 0; j < 16; ++j) wr[j] = w2[(kc * 16 + j) * 64 + c];
#pragma unroll
    for (int r = 0; r < 16; ++r) {
      const float* hp = &slice[r * 64 + kc * 16];
      const float4 za = *(const float4*)(hp + 0);
      const float4 zb = *(const float4*)(hp + 4);
      const float4 zc = *(const float4*)(hp + 8);
      const float4 zd = *(const float4*)(hp + 12);
      float a = acc2[r];
      a = fmaf(za.x, wr[0], a);  a = fmaf(za.y, wr[1], a);
      a = fmaf(za.z, wr[2], a);  a = fmaf(za.w, wr[3], a);
      a = fmaf(zb.x, wr[4], a);  a = fmaf(zb.y, wr[5], a);
      a = fmaf(zb.z, wr[6], a);  a = fmaf(zb.w, wr[7], a);
      a = fmaf(zc.x, wr[8], a);  a = fmaf(zc.y, wr[9], a);
      a = fmaf(zc.z, wr[10], a); a = fmaf(zc.w, wr[11], a);
      a = fmaf(zd.x, wr[12], a); a = fmaf(zd.y, wr[13], a);
      a = fmaf(zd.z, wr[14], a); a = fmaf(zd.w, wr[15], a);
      acc2[r] = a;
    }
  }
  // ---- store (fp16) + fused run-length pooling over sorted batch
  float pacc = 0.f;
  int cur = batch[n0];
#pragma unroll
  for (int r = 0; r < 16; ++r) {
    const float hval = fmaxf(acc2[r], 0.f);
    if (WRITEH) hout[(size_t)(n0 + r) * 64 + c] = __float2half(hval);
    const int b = batch[n0 + r];
    if (b != cur) {
      atomicAdd(&gl[(size_t)cur * 64 + c], pacc);
      pacc = 0.f;
      cur = b;
    }
    pacc += hval;
  }
  atomicAdd(&gl[(size_t)cur * 64 + c], pacc);
}

// ---------------------- JK fold + first classifier matvec (1 graph / block)
__global__ __launch_bounds__(64) void jk_fold_kernel(
    const float* __restrict__ g5, const float* __restrict__ gcnt,
    const float* __restrict__ jkw, const float* __restrict__ jkb,
    const float* __restrict__ w1, const float* __restrict__ b1,
    float* __restrict__ tmat) {
  __shared__ float sg[64];
  const int gi = blockIdx.x, c = threadIdx.x;
  float a = jkb[c] * gcnt[gi];
  for (int l = 0; l < 5; ++l) {
    const float* gv = &g5[(size_t)(l * NG + gi) * 64];
    const float* wv = &jkw[(size_t)l * 64 * 64];
#pragma unroll 8
    for (int k = 0; k < 64; ++k) a = fmaf(gv[k], wv[k * 64 + c], a);
  }
  sg[c] = a;
  __syncthreads();
  float tv = b1[c];
#pragma unroll 8
  for (int k = 0; k < 64; ++k) tv = fmaf(sg[k], w1[k * 64 + c], tv);
  tmat[gi * 64 + c] = tv;
}

// --------------------------------------------- BN (batch stats) + out matvec
__global__ __launch_bounds__(256) void bn_out_kernel(
    const float* __restrict__ tmat, const float* __restrict__ gamma,
    const float* __restrict__ beta, const float* __restrict__ w2,
    const float* __restrict__ b2, float* __restrict__ out) {
  __shared__ float sT[NG * 64];
  __shared__ float sW2[64 * OUTC];
  __shared__ float sMu[64], sRs[64];
  const int t = threadIdx.x;
  for (int i = t; i < NG * 64; i += 256) sT[i] = tmat[i];
  for (int i = t; i < 64 * OUTC; i += 256) sW2[i] = w2[i];
  __syncthreads();
  if (t < 64) {
    float s = 0.f;
    for (int gi = 0; gi < NG; ++gi) s += sT[gi * 64 + t];
    const float mu = s / NG;
    float v = 0.f;
    for (int gi = 0; gi < NG; ++gi) { const float d = sT[gi * 64 + t] - mu; v += d * d; }
    v /= NG;
    sMu[t] = mu;
    sRs[t] = rsqrtf(v + 1e-5f);
  }
  __syncthreads();
  for (int idx = t; idx < NG * 64; idx += 256) {
    const int cc = idx & 63;
    sT[idx] = fmaxf((sT[idx] - sMu[cc]) * sRs[cc] * gamma[cc] + beta[cc], 0.f);
  }
  __syncthreads();
  for (int idx = t; idx < NG * OUTC; idx += 256) {
    const int gi = idx / OUTC, o = idx % OUTC;
    float a = b2[o];
    for (int k = 0; k < 64; ++k) a = fmaf(sT[gi * 64 + k], sW2[k * OUTC + o], a);
    out[idx] = a;
  }
}

// ---------------------------------------------------------------- launch
extern "C" void kernel_launch(void* const* d_in, const int* in_sizes, int n_in,
                              void* d_out, int out_size, void* d_ws, size_t ws_size,
                              hipStream_t stream) {
  const float* x     = (const float*)d_in[0];
  const int*   ei    = (const int*)d_in[1];
  const int*   batch = (const int*)d_in[2];
  const float* w1_0  = (const float*)d_in[3];
  const float* b1_0  = (const float*)d_in[4];
  const float* w2_0  = (const float*)d_in[5];
  const float* b2_0  = (const float*)d_in[6];
  const float* w1_r  = (const float*)d_in[7];
  const float* b1_r  = (const float*)d_in[8];
  const float* w2_r  = (const float*)d_in[9];
  const float* b2_r  = (const float*)d_in[10];
  const float* jk_w  = (const float*)d_in[11];
  const float* jk_b  = (const float*)d_in[12];
  const float* cw1   = (const float*)d_in[13];
  const float* cb1   = (const float*)d_in[14];
  const float* bng   = (const float*)d_in[15];
  const float* bnb   = (const float*)d_in[16];
  const float* cw2   = (const float*)d_in[17];
  const float* cb2   = (const float*)d_in[18];
  float* out = (float*)d_out;

  char* base = (char*)d_ws;
  size_t o = 0;
  auto take = [&](size_t n) { char* p = base + o; o = (o + n + 255) & ~(size_t)255; return p; };
  int*    cnt    = (int*)take((size_t)NN * 4);
  int*    rowptr = (int*)take((size_t)(NN + 1) * 4);
  int*    cursor = (int*)take((size_t)NN * 4);
  int*    part   = (int*)take((size_t)SCAN_NB * 4);
  int*    esrc   = (int*)take((size_t)NE * 4);
  __half* hA     = (__half*)take((size_t)NN * 64 * 2);
  __half* hB     = (__half*)take((size_t)NN * 64 * 2);
  float*  g5     = (float*)take((size_t)5 * NG * 64 * 4);
  float*  gcnt   = (float*)take((size_t)NG * 4);
  float*  tmat   = (float*)take((size_t)NG * 64 * 4);
  (void)ws_size; (void)in_sizes; (void)n_in; (void)out_size;

  hipMemsetAsync(cnt, 0, (size_t)NN * 4, stream);
  hipMemsetAsync(g5, 0, (size_t)5 * NG * 64 * 4, stream);

  const int* src = ei;
  const int* dst = ei + NE;
  count_kernel<<<1024, 256, 0, stream>>>(dst, cnt);
  partial_kernel<<<SCAN_NB, 256, 0, stream>>>(cnt, part);
  scanpart_kernel<<<1, 256, 0, stream>>>(part);
  scatter_scan_kernel<<<SCAN_NB, 256, 0, stream>>>(cnt, part, rowptr, cursor);
  fill_kernel<<<1024, 256, 0, stream>>>(src, dst, cursor, esrc);
  gbounds_kernel<<<1, 128, 0, stream>>>(batch, gcnt);

  const int GRID = (NTILE + 3) / 4;  // 782

  // layer 0 (pre-projected): y = x@W1_0 (into hB fp16), then fused w/o W1
  proj_kernel<<<512, 256, 0, stream>>>(x, w1_0, hB);
  gin_fused_kernel<false, true><<<GRID, 256, 0, stream>>>(
      hB, rowptr, esrc, nullptr, b1_0, w2_0, b2_0, hA, batch, g5);
  const __half* hin = hA;
  __half* hout = hB;
  for (int l = 1; l < 5; ++l) {
    if (l < 4) {
      gin_fused_kernel<true, true><<<GRID, 256, 0, stream>>>(
          hin, rowptr, esrc, w1_r + (size_t)(l - 1) * 64 * 64,
          b1_r + (size_t)(l - 1) * 64, w2_r + (size_t)(l - 1) * 64 * 64,
          b2_r + (size_t)(l - 1) * 64, hout, batch, g5 + (size_t)l * NG * 64);
    } else {
      // last layer: h5 is only pooled -> skip the dead hout store
      gin_fused_kernel<true, false><<<GRID, 256, 0, stream>>>(
          hin, rowptr, esrc, w1_r + (size_t)(l - 1) * 64 * 64,
          b1_r + (size_t)(l - 1) * 64, w2_r + (size_t)(l - 1) * 64 * 64,
          b2_r + (size_t)(l - 1) * 64, hout, batch, g5 + (size_t)l * NG * 64);
    }
    __half* tmp = (__half*)hin;
    hin = hout;
    hout = tmp;
  }

  jk_fold_kernel<<<NG, 64, 0, stream>>>(g5, gcnt, jk_w, jk_b, cw1, cb1, tmat);
  bn_out_kernel<<<1, 256, 0, stream>>>(tmat, bng, bnb, cw2, cb2, out);
}

// Round 13
// 390.919 us; speedup vs baseline: 6.8446x; 1.0111x over previous
//
#include <hip/hip_runtime.h>
#include <hip/hip_fp16.h>

#define NN 50000
#define NE 800000
#define NG 128
#define OUTC 10
#define SCAN_NB ((NN + 255) / 256)  // 196
#define NTILE 3125                  // 50000 / 16 exactly
#define NODES_PER_PART 6250         // NN / 8
#define FILL_CH 6250                // NE / 128

// ---------------------------------------------------------------- CSR build
__global__ void count_kernel(const int* __restrict__ dst, int* __restrict__ cnt) {
  const int idx = blockIdx.x * blockDim.x + threadIdx.x;
  if (idx < NE / 4) {
    const int4 d = ((const int4*)dst)[idx];
    atomicAdd(&cnt[d.x], 1);
    atomicAdd(&cnt[d.y], 1);
    atomicAdd(&cnt[d.z], 1);
    atomicAdd(&cnt[d.w], 1);
  }
}

__global__ __launch_bounds__(256) void partial_kernel(const int* __restrict__ cnt,
                                                      int* __restrict__ part) {
  __shared__ int red[256];
  const int t = threadIdx.x;
  const int idx = blockIdx.x * 256 + t;
  red[t] = (idx < NN) ? cnt[idx] : 0;
  __syncthreads();
#pragma unroll
  for (int off = 128; off > 0; off >>= 1) {
    if (t < off) red[t] += red[t + off];
    __syncthreads();
  }
  if (t == 0) part[blockIdx.x] = red[0];
}

// scatter_scan with the 196-partial scan folded in (scanpart_kernel deleted:
// every block redoes the tiny scan in LDS -- cheaper than a dispatch).
__global__ __launch_bounds__(256) void scatter_scan_kernel(const int* __restrict__ cnt,
                                                           const int* __restrict__ part,
                                                           int* __restrict__ rowptr,
                                                           int* __restrict__ cursor) {
  __shared__ int s[256];
  __shared__ int sp[256];
  const int t = threadIdx.x;
  sp[t] = (t < SCAN_NB) ? part[t] : 0;
  const int idx = blockIdx.x * 256 + t;
  s[t] = (idx < NN) ? cnt[idx] : 0;
  __syncthreads();
#pragma unroll
  for (int off = 1; off < 256; off <<= 1) {
    const int v = (t >= off) ? s[t - off] : 0;
    const int vp = (t >= off) ? sp[t - off] : 0;
    __syncthreads();
    s[t] += v;
    sp[t] += vp;
    __syncthreads();
  }
  const int pbase = (blockIdx.x == 0) ? 0 : sp[blockIdx.x - 1];
  const int excl = pbase + ((t == 0) ? 0 : s[t - 1]);
  if (idx < NN) { rowptr[idx] = excl; cursor[idx] = excl; }
  if (idx == 0) rowptr[NN] = NE;
}

// Partitioned fill: block b covers dst-partition (b&7) over edge chunk (b>>3).
__global__ __launch_bounds__(256) void fill_kernel(const int* __restrict__ src,
                                                   const int* __restrict__ dst,
                                                   int* __restrict__ cursor,
                                                   int* __restrict__ esrc) {
  const int p = blockIdx.x & 7;
  const int q = blockIdx.x >> 3;
  const int lo = p * NODES_PER_PART, hi = lo + NODES_PER_PART;
  const int e0 = q * FILL_CH, e1 = e0 + FILL_CH;
  for (int e = e0 + threadIdx.x; e < e1; e += 256) {
    const int d = dst[e];
    if (d >= lo && d < hi) {
      const int pos = atomicAdd(&cursor[d], 1);
      esrc[pos] = src[e];
    }
  }
}

// ------------------------------------------------- proj: y = x @ W1_0 (fp16)
__global__ __launch_bounds__(256) void proj_kernel(const float* __restrict__ x,
                                                   const float* __restrict__ w1,
                                                   __half* __restrict__ y) {
  __shared__ float sW[128 * 64];
  __shared__ float sX[64 * 128];
  const int t = threadIdx.x, c = t & 63, rg = t >> 6;
  for (int i = t; i < 128 * 64; i += 256) sW[i] = w1[i];
  const int ntiles = (NN + 63) / 64;
  for (int tile = blockIdx.x; tile < ntiles; tile += gridDim.x) {
    const int r0 = tile * 64, nv = min(64, NN - r0);
    __syncthreads();
    for (int i = t; i < nv * 32; i += 256)
      ((float4*)sX)[i] = ((const float4*)(x + (size_t)r0 * 128))[i];
    __syncthreads();
    float acc[16];
#pragma unroll
    for (int i = 0; i < 16; ++i) acc[i] = 0.f;
    for (int k = 0; k < 128; k += 4) {
      const float w0 = sW[(k + 0) * 64 + c], w1v = sW[(k + 1) * 64 + c],
                  w2v = sW[(k + 2) * 64 + c], w3v = sW[(k + 3) * 64 + c];
#pragma unroll
      for (int i = 0; i < 16; ++i) {
        const float4 xv = *(const float4*)&sX[(rg * 16 + i) * 128 + k];
        acc[i] = fmaf(xv.x, w0, acc[i]);
        acc[i] = fmaf(xv.y, w1v, acc[i]);
        acc[i] = fmaf(xv.z, w2v, acc[i]);
        acc[i] = fmaf(xv.w, w3v, acc[i]);
      }
    }
#pragma unroll
    for (int i = 0; i < 16; ++i) {
      const int r = rg * 16 + i;
      if (r < nv) y[(size_t)(r0 + r) * 64 + c] = __float2half(acc[i]);
    }
  }
}

// --------------------------------------- FUSED GIN layer: gather + MLP + pool
// r12 body with ONE change: gather accumulates in fp16 via __hadd2 (8 packed
// adds per 2 edges vs 32 cvt+add), converting to fp32 once after the loop.
// Tile geometry, lane mapping, matvecs: byte-identical to r11/r12.
// DO NOT restructure tiles or add launch_bounds min-waves (r8/r9/r10 lessons).
template <bool HASW1, bool WRITEH>
__global__ __launch_bounds__(256) void gin_fused_kernel(
    const __half* __restrict__ hin, const int* __restrict__ rowptr,
    const int* __restrict__ esrc,
    const float* __restrict__ w1, const float* __restrict__ b1,
    const float* __restrict__ w2, const float* __restrict__ b2,
    __half* __restrict__ hout, const int* __restrict__ batch,
    float* __restrict__ gl) {
  __shared__ float sS[4][16 * 64];  // 16KB/block
  const int t = threadIdx.x, c = t & 63, wv = t >> 6;
  const int wg = blockIdx.x * 4 + wv;
  if (wg >= NTILE) return;  // no barriers anywhere: safe
  float* slice = &sS[wv][0];
  const int n0 = wg * 16;
  const int oct = c >> 3, i = c & 7;  // lane covers channels [i*8, i*8+8)

  // ---- gather phase: rows rA = n0+2*oct, rB = rA+1 (fp16 accumulation)
  const int rA = n0 + 2 * oct;
  const int pA0 = rowptr[rA], pA1 = rowptr[rA + 1], pB1 = rowptr[rA + 2];
  union H8 { float4 f; __half2 h2[4]; };
  const __half* hch = hin + i * 8;
  __half2 zA2[4], zB2[4];
  {
    H8 u0, u1;
    u0.f = *(const float4*)(hch + (size_t)rA * 64);        // self terms
    u1.f = *(const float4*)(hch + (size_t)(rA + 1) * 64);
#pragma unroll
    for (int k = 0; k < 4; ++k) { zA2[k] = u0.h2[k]; zB2[k] = u1.h2[k]; }
  }
  int eA = pA0, eB = pA1;
  while (eA + 1 < pA1 && eB + 1 < pB1) {
    const int sA0 = esrc[eA], sA1 = esrc[eA + 1];
    const int sB0 = esrc[eB], sB1 = esrc[eB + 1];
    H8 a0, a1, b0, b1v;
    a0.f = *(const float4*)(hch + (size_t)sA0 * 64);
    a1.f = *(const float4*)(hch + (size_t)sA1 * 64);
    b0.f = *(const float4*)(hch + (size_t)sB0 * 64);
    b1v.f = *(const float4*)(hch + (size_t)sB1 * 64);
#pragma unroll
    for (int k = 0; k < 4; ++k) {
      zA2[k] = __hadd2(zA2[k], __hadd2(a0.h2[k], a1.h2[k]));
      zB2[k] = __hadd2(zB2[k], __hadd2(b0.h2[k], b1v.h2[k]));
    }
    eA += 2; eB += 2;
  }
  for (; eA + 1 < pA1; eA += 2) {
    const int s0 = esrc[eA], s1 = esrc[eA + 1];
    H8 u0, u1;
    u0.f = *(const float4*)(hch + (size_t)s0 * 64);
    u1.f = *(const float4*)(hch + (size_t)s1 * 64);
#pragma unroll
    for (int k = 0; k < 4; ++k) zA2[k] = __hadd2(zA2[k], __hadd2(u0.h2[k], u1.h2[k]));
  }
  if (eA < pA1) {
    H8 u0; u0.f = *(const float4*)(hch + (size_t)esrc[eA] * 64);
#pragma unroll
    for (int k = 0; k < 4; ++k) zA2[k] = __hadd2(zA2[k], u0.h2[k]);
  }
  for (; eB + 1 < pB1; eB += 2) {
    const int s0 = esrc[eB], s1 = esrc[eB + 1];
    H8 u0, u1;
    u0.f = *(const float4*)(hch + (size_t)s0 * 64);
    u1.f = *(const float4*)(hch + (size_t)s1 * 64);
#pragma unroll
    for (int k = 0; k < 4; ++k) zB2[k] = __hadd2(zB2[k], __hadd2(u0.h2[k], u1.h2[k]));
  }
  if (eB < pB1) {
    H8 u0; u0.f = *(const float4*)(hch + (size_t)esrc[eB] * 64);
#pragma unroll
    for (int k = 0; k < 4; ++k) zB2[k] = __hadd2(zB2[k], u0.h2[k]);
  }
  // unpack to fp32 once
  float zA[8], zB[8];
#pragma unroll
  for (int k = 0; k < 4; ++k) {
    const float2 fa = __half22float2(zA2[k]);
    const float2 fb = __half22float2(zB2[k]);
    zA[2 * k] = fa.x; zA[2 * k + 1] = fa.y;
    zB[2 * k] = fb.x; zB[2 * k + 1] = fb.y;
  }
  if (!HASW1) {  // layer 0 (pre-projected): h1 = relu(z + b1) fused here
    const float4 blo = *(const float4*)(b1 + i * 8);
    const float4 bhi = *(const float4*)(b1 + i * 8 + 4);
    zA[0] = fmaxf(zA[0] + blo.x, 0.f); zA[1] = fmaxf(zA[1] + blo.y, 0.f);
    zA[2] = fmaxf(zA[2] + blo.z, 0.f); zA[3] = fmaxf(zA[3] + blo.w, 0.f);
    zA[4] = fmaxf(zA[4] + bhi.x, 0.f); zA[5] = fmaxf(zA[5] + bhi.y, 0.f);
    zA[6] = fmaxf(zA[6] + bhi.z, 0.f); zA[7] = fmaxf(zA[7] + bhi.w, 0.f);
    zB[0] = fmaxf(zB[0] + blo.x, 0.f); zB[1] = fmaxf(zB[1] + blo.y, 0.f);
    zB[2] = fmaxf(zB[2] + blo.z, 0.f); zB[3] = fmaxf(zB[3] + blo.w, 0.f);
    zB[4] = fmaxf(zB[4] + bhi.x, 0.f); zB[5] = fmaxf(zB[5] + bhi.y, 0.f);
    zB[6] = fmaxf(zB[6] + bhi.z, 0.f); zB[7] = fmaxf(zB[7] + bhi.w, 0.f);
  }
  {
    const float4 a0 = {zA[0], zA[1], zA[2], zA[3]};
    const float4 a1 = {zA[4], zA[5], zA[6], zA[7]};
    const float4 b0v = {zB[0], zB[1], zB[2], zB[3]};
    const float4 b1v_ = {zB[4], zB[5], zB[6], zB[7]};
    *(float4*)&slice[(2 * oct) * 64 + i * 8] = a0;
    *(float4*)&slice[(2 * oct) * 64 + i * 8 + 4] = a1;
    *(float4*)&slice[(2 * oct + 1) * 64 + i * 8] = b0v;
    *(float4*)&slice[(2 * oct + 1) * 64 + i * 8 + 4] = b1v_;
  }
  // same-wave LDS: DS pipe is in-order per wave -> no barrier needed

  const float b1c = b1[c], b2c = b2[c];
  // ---- matvec1: h1 = relu(z @ W1 + b1)
  if (HASW1) {
    float acc[16];
#pragma unroll
    for (int r = 0; r < 16; ++r) acc[r] = b1c;
    for (int kc = 0; kc < 4; ++kc) {
      float wr[16];
#pragma unroll
      for (int j = 0; j < 16; ++j) wr[j] = w1[(kc * 16 + j) * 64 + c];
#pragma unroll
      for (int r = 0; r < 16; ++r) {
        const float* zp = &slice[r * 64 + kc * 16];
        const float4 za = *(const float4*)(zp + 0);
        const float4 zb = *(const float4*)(zp + 4);
        const float4 zc = *(const float4*)(zp + 8);
        const float4 zd = *(const float4*)(zp + 12);
        float a = acc[r];
        a = fmaf(za.x, wr[0], a);  a = fmaf(za.y, wr[1], a);
        a = fmaf(za.z, wr[2], a);  a = fmaf(za.w, wr[3], a);
        a = fmaf(zb.x, wr[4], a);  a = fmaf(zb.y, wr[5], a);
        a = fmaf(zb.z, wr[6], a);  a = fmaf(zb.w, wr[7], a);
        a = fmaf(zc.x, wr[8], a);  a = fmaf(zc.y, wr[9], a);
        a = fmaf(zc.z, wr[10], a); a = fmaf(zc.w, wr[11], a);
        a = fmaf(zd.x, wr[12], a); a = fmaf(zd.y, wr[13], a);
        a = fmaf(zd.z, wr[14], a); a = fmaf(zd.w, wr[15], a);
        acc[r] = a;
      }
    }
#pragma unroll
    for (int r = 0; r < 16; ++r) slice[r * 64 + c] = fmaxf(acc[r], 0.f);
  }

  // ---- matvec2: h = relu(h1 @ W2 + b2)
  float acc2[16];
#pragma unroll
  for (int r = 0; r < 16; ++r) acc2[r] = b2c;
  for (int kc = 0; kc < 4; ++kc) {
    float wr[16];
#pragma unroll
    for (int j = 0; j < 16; ++j) wr[j] = w2[(kc * 16 + j) * 64 + c];
#pragma unroll
    for (int r = 0; r < 16; ++r) {
      const float* hp = &slice[r * 64 + kc * 16];
      const float4 za = *(const float4*)(hp + 0);
      const float4 zb = *(const float4*)(hp + 4);
      const float4 zc = *(const float4*)(hp + 8);
      const float4 zd = *(const float4*)(hp + 12);
      float a = acc2[r];
      a = fmaf(za.x, wr[0], a);  a = fmaf(za.y, wr[1], a);
      a = fmaf(za.z, wr[2], a);  a = fmaf(za.w, wr[3], a);
      a = fmaf(zb.x, wr[4], a);  a = fmaf(zb.y, wr[5], a);
      a = fmaf(zb.z, wr[6], a);  a = fmaf(zb.w, wr[7], a);
      a = fmaf(zc.x, wr[8], a);  a = fmaf(zc.y, wr[9], a);
      a = fmaf(zc.z, wr[10], a); a = fmaf(zc.w, wr[11], a);
      a = fmaf(zd.x, wr[12], a); a = fmaf(zd.y, wr[13], a);
      a = fmaf(zd.z, wr[14], a); a = fmaf(zd.w, wr[15], a);
      acc2[r] = a;
    }
  }
  // ---- store (fp16) + fused run-length pooling over sorted batch
  float pacc = 0.f;
  int cur = batch[n0];
#pragma unroll
  for (int r = 0; r < 16; ++r) {
    const float hval = fmaxf(acc2[r], 0.f);
    if (WRITEH) hout[(size_t)(n0 + r) * 64 + c] = __float2half(hval);
    const int b = batch[n0 + r];
    if (b != cur) {
      atomicAdd(&gl[(size_t)cur * 64 + c], pacc);
      pacc = 0.f;
      cur = b;
    }
    pacc += hval;
  }
  atomicAdd(&gl[(size_t)cur * 64 + c], pacc);
}

// ------- JK fold + first classifier matvec (1 graph / block, self gbounds)
__global__ __launch_bounds__(64) void jk_fold_kernel(
    const float* __restrict__ g5, const int* __restrict__ batch,
    const float* __restrict__ jkw, const float* __restrict__ jkb,
    const float* __restrict__ w1, const float* __restrict__ b1,
    float* __restrict__ tmat) {
  __shared__ float sg[64];
  const int gi = blockIdx.x, c = threadIdx.x;
  // node count for this graph via two binary searches (batch sorted)
  int lo = 0, hi = NN;
  while (lo < hi) { const int m = (lo + hi) >> 1; if (batch[m] < gi) lo = m + 1; else hi = m; }
  int lo2 = lo, hi2 = NN;
  while (lo2 < hi2) { const int m = (lo2 + hi2) >> 1; if (batch[m] < gi + 1) lo2 = m + 1; else hi2 = m; }
  const float cntg = (float)(lo2 - lo);
  float a = jkb[c] * cntg;
  for (int l = 0; l < 5; ++l) {
    const float* gv = &g5[(size_t)(l * NG + gi) * 64];
    const float* wv = &jkw[(size_t)l * 64 * 64];
#pragma unroll 8
    for (int k = 0; k < 64; ++k) a = fmaf(gv[k], wv[k * 64 + c], a);
  }
  sg[c] = a;
  __syncthreads();
  float tv = b1[c];
#pragma unroll 8
  for (int k = 0; k < 64; ++k) tv = fmaf(sg[k], w1[k * 64 + c], tv);
  tmat[gi * 64 + c] = tv;
}

// --------------------------------------------- BN (batch stats) + out matvec
__global__ __launch_bounds__(256) void bn_out_kernel(
    const float* __restrict__ tmat, const float* __restrict__ gamma,
    const float* __restrict__ beta, const float* __restrict__ w2,
    const float* __restrict__ b2, float* __restrict__ out) {
  __shared__ float sT[NG * 64];
  __shared__ float sW2[64 * OUTC];
  __shared__ float sMu[64], sRs[64];
  const int t = threadIdx.x;
  for (int i = t; i < NG * 64; i += 256) sT[i] = tmat[i];
  for (int i = t; i < 64 * OUTC; i += 256) sW2[i] = w2[i];
  __syncthreads();
  if (t < 64) {
    float s = 0.f;
    for (int gi = 0; gi < NG; ++gi) s += sT[gi * 64 + t];
    const float mu = s / NG;
    float v = 0.f;
    for (int gi = 0; gi < NG; ++gi) { const float d = sT[gi * 64 + t] - mu; v += d * d; }
    v /= NG;
    sMu[t] = mu;
    sRs[t] = rsqrtf(v + 1e-5f);
  }
  __syncthreads();
  for (int idx = t; idx < NG * 64; idx += 256) {
    const int cc = idx & 63;
    sT[idx] = fmaxf((sT[idx] - sMu[cc]) * sRs[cc] * gamma[cc] + beta[cc], 0.f);
  }
  __syncthreads();
  for (int idx = t; idx < NG * OUTC; idx += 256) {
    const int gi = idx / OUTC, o = idx % OUTC;
    float a = b2[o];
    for (int k = 0; k < 64; ++k) a = fmaf(sT[gi * 64 + k], sW2[k * OUTC + o], a);
    out[idx] = a;
  }
}

// ---------------------------------------------------------------- launch
extern "C" void kernel_launch(void* const* d_in, const int* in_sizes, int n_in,
                              void* d_out, int out_size, void* d_ws, size_t ws_size,
                              hipStream_t stream) {
  const float* x     = (const float*)d_in[0];
  const int*   ei    = (const int*)d_in[1];
  const int*   batch = (const int*)d_in[2];
  const float* w1_0  = (const float*)d_in[3];
  const float* b1_0  = (const float*)d_in[4];
  const float* w2_0  = (const float*)d_in[5];
  const float* b2_0  = (const float*)d_in[6];
  const float* w1_r  = (const float*)d_in[7];
  const float* b1_r  = (const float*)d_in[8];
  const float* w2_r  = (const float*)d_in[9];
  const float* b2_r  = (const float*)d_in[10];
  const float* jk_w  = (const float*)d_in[11];
  const float* jk_b  = (const float*)d_in[12];
  const float* cw1   = (const float*)d_in[13];
  const float* cb1   = (const float*)d_in[14];
  const float* bng   = (const float*)d_in[15];
  const float* bnb   = (const float*)d_in[16];
  const float* cw2   = (const float*)d_in[17];
  const float* cb2   = (const float*)d_in[18];
  float* out = (float*)d_out;

  char* base = (char*)d_ws;
  size_t o = 0;
  auto take = [&](size_t n) { char* p = base + o; o = (o + n + 255) & ~(size_t)255; return p; };
  int*    cnt    = (int*)take((size_t)NN * 4);
  int*    rowptr = (int*)take((size_t)(NN + 1) * 4);
  int*    cursor = (int*)take((size_t)NN * 4);
  int*    part   = (int*)take((size_t)SCAN_NB * 4);
  int*    esrc   = (int*)take((size_t)NE * 4);
  __half* hA     = (__half*)take((size_t)NN * 64 * 2);
  __half* hB     = (__half*)take((size_t)NN * 64 * 2);
  float*  g5     = (float*)take((size_t)5 * NG * 64 * 4);
  float*  tmat   = (float*)take((size_t)NG * 64 * 4);
  (void)ws_size; (void)in_sizes; (void)n_in; (void)out_size;

  hipMemsetAsync(cnt, 0, (size_t)NN * 4, stream);
  hipMemsetAsync(g5, 0, (size_t)5 * NG * 64 * 4, stream);

  const int* src = ei;
  const int* dst = ei + NE;
  count_kernel<<<(NE / 4 + 255) / 256, 256, 0, stream>>>(dst, cnt);
  partial_kernel<<<SCAN_NB, 256, 0, stream>>>(cnt, part);
  scatter_scan_kernel<<<SCAN_NB, 256, 0, stream>>>(cnt, part, rowptr, cursor);
  fill_kernel<<<1024, 256, 0, stream>>>(src, dst, cursor, esrc);

  const int GRID = (NTILE + 3) / 4;  // 782

  // layer 0 (pre-projected): y = x@W1_0 (into hB fp16), then fused w/o W1
  proj_kernel<<<512, 256, 0, stream>>>(x, w1_0, hB);
  gin_fused_kernel<false, true><<<GRID, 256, 0, stream>>>(
      hB, rowptr, esrc, nullptr, b1_0, w2_0, b2_0, hA, batch, g5);
  const __half* hin = hA;
  __half* hout = hB;
  for (int l = 1; l < 5; ++l) {
    if (l < 4) {
      gin_fused_kernel<true, true><<<GRID, 256, 0, stream>>>(
          hin, rowptr, esrc, w1_r + (size_t)(l - 1) * 64 * 64,
          b1_r + (size_t)(l - 1) * 64, w2_r + (size_t)(l - 1) * 64 * 64,
          b2_r + (size_t)(l - 1) * 64, hout, batch, g5 + (size_t)l * NG * 64);
    } else {
      // last layer: h5 is only pooled -> skip the dead hout store
      gin_fused_kernel<true, false><<<GRID, 256, 0, stream>>>(
          hin, rowptr, esrc, w1_r + (size_t)(l - 1) * 64 * 64,
          b1_r + (size_t)(l - 1) * 64, w2_r + (size_t)(l - 1) * 64 * 64,
          b2_r + (size_t)(l - 1) * 64, hout, batch, g5 + (size_t)l * NG * 64);
    }
    __half* tmp = (__half*)hin;
    hin = hout;
    hout = tmp;
  }

  jk_fold_kernel<<<NG, 64, 0, stream>>>(g5, batch, jk_w, jk_b, cw1, cb1, tmat);
  bn_out_kernel<<<1, 256, 0, stream>>>(tmat, bng, bnb, cw2, cb2, out);
}